// Round 17
// baseline (90.384 us; speedup 1.0000x reference)
//
#include <hip/hip_runtime.h>
#include <hip/hip_bf16.h>
#include <math.h>

// Problem constants
#define BB   2
#define CC   256
#define LL   2048
#define DD   64
#define HH   8
#define HDIM 512
#define BLQ  (BB*LL)      // 4096 tokens
#define EPSV 1e-8f
#define QSCALE (0.125f * 1.44269504088896f)   // 1/sqrt(64) * log2(e): softmax in exp2 domain

typedef __attribute__((ext_vector_type(8))) short short8;    // 8 bf16 (4 VGPRs)
typedef __attribute__((ext_vector_type(4))) float f32x4;     // 16x16 MFMA acc
typedef __attribute__((ext_vector_type(16))) float f32x16;   // 32x32 MFMA acc

// ---------------- helpers ----------------
__device__ __forceinline__ float wred_sum(float v) {
#pragma unroll
    for (int off = 32; off > 0; off >>= 1) v += __shfl_down(v, off, 64);
    return v;
}
// HW packed fp32x2 -> bf16x2 (RNE), single v_cvt_pk_bf16_f32
__device__ __forceinline__ unsigned pk(float a, float b) {
    unsigned r;
    asm("v_cvt_pk_bf16_f32 %0, %1, %2" : "=v"(r) : "v"(a), "v"(b));
    return r;
}
// bare HW exp2 / log2 (softmax runs in the exp2 domain; libm paths are multi-instr)
__device__ __forceinline__ float ex2(float x) {
    float r;
    asm("v_exp_f32 %0, %1" : "=v"(r) : "v"(x));
    return r;
}
__device__ __forceinline__ float lg2(float x) {
    float r;
    asm("v_log_f32 %0, %1" : "=v"(r) : "v"(x));
    return r;
}
__device__ __forceinline__ float bf2f(unsigned short v) {
    union { unsigned u; float f; } c; c.u = ((unsigned)v) << 16; return c.f;
}
// cross-half register swap: x[0:31] <-> y[32:63]  (v_permlane32_swap_b32; verified r6)
__device__ __forceinline__ void pswap(unsigned &x, unsigned &y) {
    asm("v_permlane32_swap_b32 %0, %1" : "+v"(x), "+v"(y));
}
__device__ __forceinline__ short8 mk8(unsigned x0, unsigned x1, unsigned x2, unsigned x3) {
    union { short8 v; unsigned u[4]; } r;
    r.u[0] = x0; r.u[1] = x1; r.u[2] = x2; r.u[3] = x3;
    return r.v;
}
// assemble a bf16x8 fragment from two 8B LDS loads (stride-68, measured-low-conflict)
__device__ __forceinline__ short8 ld_frag(const unsigned short* p) {
    union { short8 v; uint2 u[2]; } f;
    f.u[0] = *(const uint2*)p;
    f.u[1] = *(const uint2*)(p + 4);
    return f.v;
}

// ---------------- prep (fused): t = x^T + PE  AND  weight fp32->bf16 convert ----------
__global__ __launch_bounds__(256) void k_prep(const float* __restrict__ x,
                                              const float* __restrict__ Wq, const float* __restrict__ Wk,
                                              const float* __restrict__ Wv, const float* __restrict__ Wo,
                                              const float* __restrict__ Wc,
                                              float* __restrict__ t,
                                              unsigned short* __restrict__ tb,
                                              unsigned short* __restrict__ dqkv,
                                              unsigned short* __restrict__ dWo,
                                              unsigned short* __restrict__ dWc) {
    int bid = blockIdx.x;
    int tid = threadIdx.x;
    if (bid >= 256) {   // ---- weight convert: 576 blocks * 256 thr * 4 elems ----
        int idx = ((bid - 256) * 256 + tid) * 4;
        const float* s; unsigned short* d;
        if (idx < 131072)      { s = Wq + idx;          d = dqkv + idx; }
        else if (idx < 262144) { s = Wk + idx - 131072; d = dqkv + idx; }
        else if (idx < 393216) { s = Wv + idx - 262144; d = dqkv + idx; }
        else if (idx < 524288) { s = Wo + idx - 393216; d = dWo + idx - 393216; }
        else                   { s = Wc + idx - 524288; d = dWc + idx - 524288; }
        float4 v = *(const float4*)s;
        uint2 u; u.x = pk(v.x, v.y); u.y = pk(v.z, v.w);
        *(uint2*)d = u;
        return;
    }
    // ---- transpose + positional encoding ----
    __shared__ float tr[64][65];    // [l][c]
    int l0 = (bid & 31) * 64, c0 = ((bid >> 5) & 3) * 64, b = bid >> 7;
    int r = tid >> 2, q = tid & 3;
#pragma unroll
    for (int p = 0; p < 4; ++p) {
        int lc = 4 * (q + 4 * p);
        float4 v = *(const float4*)&x[((size_t)(b * CC + c0 + r)) * LL + l0 + lc];
        tr[lc + 0][r] = v.x; tr[lc + 1][r] = v.y; tr[lc + 2][r] = v.z; tr[lc + 3][r] = v.w;
    }
    __syncthreads();
    int lg = l0 + r;
#pragma unroll
    for (int p = 0; p < 4; ++p) {
        int cc = 4 * (q + 4 * p);
        float4 v = *(const float4*)&tr[r][cc];
        float pe[4];
#pragma unroll
        for (int i = 0; i < 4; ++i) {
            int cg = c0 + cc + i;
            float freq = __expf((float)(cg & ~1) * (-9.210340371976184f / (float)CC));
            float ang = (float)lg * freq;
            pe[i] = (cg & 1) ? __cosf(ang) : __sinf(ang);
        }
        v.x += pe[0]; v.y += pe[1]; v.z += pe[2]; v.w += pe[3];
        size_t o = ((size_t)(b * LL + lg)) * CC + c0 + cc;
        *(float4*)&t[o] = v;
        uint2 u; u.x = pk(v.x, v.y); u.y = pk(v.z, v.w);
        *(uint2*)&tb[o] = u;
    }
}

// ---------------- QKV GEMM: 128x128 tile, BK=64, 32x32 MFMA (guide ladder: 64^2->128^2) --
// A: (M=4096, K=256) bf16; W: (1536, 256) bf16 rows [0,512)=Q, [512,1024)=K, [1024,1536)=V.
// 4 waves in 2x2 (wr = N-dim, wc = M-dim); each wave 64x64 via 2x2 f32x16 fragments.
// N-tile 128 never straddles a 512-seg boundary -> whole block is Q-, K-, or V-only.
// Q/K stored (B,H,L,D) bf16 (Q x QSCALE); V stored transposed (B,H,D,L) via swapped MFMA.
// C/D layout (32x32): col = lane&31, row = (reg&3) + 8*(reg>>2) + 4*(lane>>5).
#define QLDK 68
__global__ __launch_bounds__(256) void k_mmq(const unsigned short* __restrict__ A,
                                             const unsigned short* __restrict__ W,
                                             const float* __restrict__ bqv,
                                             const float* __restrict__ bkv,
                                             const float* __restrict__ bvv,
                                             unsigned short* __restrict__ outb) {
    __shared__ unsigned short As[2][128][QLDK];
    __shared__ unsigned short Ws[2][128][QLDK];
    int tid = threadIdx.x;
    int w = tid >> 6, lane = tid & 63;
    int lo31 = lane & 31, hi = lane >> 5;
    int wr = w >> 1, wc = w & 1;
    int bm = blockIdx.x * 128, bn = blockIdx.y * 128;
    int srow = tid >> 1, sq = tid & 1;           // staging: 2 thr/row, 4 uint4 each
    bool vseg = (bn >= 1024);
    const int K = CC;
    f32x16 acc[2][2];                            // [n-frag rb][token-frag cb]
#pragma unroll
    for (int i = 0; i < 2; ++i)
#pragma unroll
        for (int j = 0; j < 2; ++j)
#pragma unroll
            for (int r = 0; r < 16; ++r) acc[i][j][r] = 0.f;
    uint4 ra[4], rw[4];
#pragma unroll
    for (int j = 0; j < 4; ++j) {
        ra[j] = *(const uint4*)&A[(size_t)(bm + srow) * K + sq * 32 + j * 8];
        rw[j] = *(const uint4*)&W[(size_t)(bn + srow) * K + sq * 32 + j * 8];
    }
    for (int it = 0; it < 4; ++it) {             // K = 4 x 64
        int buf = it & 1;
#pragma unroll
        for (int j = 0; j < 4; ++j) {
            *(uint2*)&As[buf][srow][sq * 32 + j * 8]     = make_uint2(ra[j].x, ra[j].y);
            *(uint2*)&As[buf][srow][sq * 32 + j * 8 + 4] = make_uint2(ra[j].z, ra[j].w);
            *(uint2*)&Ws[buf][srow][sq * 32 + j * 8]     = make_uint2(rw[j].x, rw[j].y);
            *(uint2*)&Ws[buf][srow][sq * 32 + j * 8 + 4] = make_uint2(rw[j].z, rw[j].w);
        }
        __syncthreads();
        if (it + 1 < 4) {
            int k0 = (it + 1) << 6;
#pragma unroll
            for (int j = 0; j < 4; ++j) {
                ra[j] = *(const uint4*)&A[(size_t)(bm + srow) * K + k0 + sq * 32 + j * 8];
                rw[j] = *(const uint4*)&W[(size_t)(bn + srow) * K + k0 + sq * 32 + j * 8];
            }
        }
#pragma unroll
        for (int ks = 0; ks < 4; ++ks) {
            short8 wf0 = ld_frag(&Ws[buf][wr * 64 +      lo31][ks * 16 + 8 * hi]);
            short8 wf1 = ld_frag(&Ws[buf][wr * 64 + 32 + lo31][ks * 16 + 8 * hi]);
            short8 af0 = ld_frag(&As[buf][wc * 64 +      lo31][ks * 16 + 8 * hi]);
            short8 af1 = ld_frag(&As[buf][wc * 64 + 32 + lo31][ks * 16 + 8 * hi]);
            if (!vseg) {                         // col = token, row = n
                acc[0][0] = __builtin_amdgcn_mfma_f32_32x32x16_bf16(wf0, af0, acc[0][0], 0, 0, 0);
                acc[0][1] = __builtin_amdgcn_mfma_f32_32x32x16_bf16(wf0, af1, acc[0][1], 0, 0, 0);
                acc[1][0] = __builtin_amdgcn_mfma_f32_32x32x16_bf16(wf1, af0, acc[1][0], 0, 0, 0);
                acc[1][1] = __builtin_amdgcn_mfma_f32_32x32x16_bf16(wf1, af1, acc[1][1], 0, 0, 0);
            } else {                             // swapped: col = n (d), row = token
                acc[0][0] = __builtin_amdgcn_mfma_f32_32x32x16_bf16(af0, wf0, acc[0][0], 0, 0, 0);
                acc[0][1] = __builtin_amdgcn_mfma_f32_32x32x16_bf16(af1, wf0, acc[0][1], 0, 0, 0);
                acc[1][0] = __builtin_amdgcn_mfma_f32_32x32x16_bf16(af0, wf1, acc[1][0], 0, 0, 0);
                acc[1][1] = __builtin_amdgcn_mfma_f32_32x32x16_bf16(af1, wf1, acc[1][1], 0, 0, 0);
            }
        }
    }
    if (!vseg) {
        int seg = bn >> 9;                       // 0 = Q, 1 = K
        const float* bs = seg ? bkv : bqv;
        float sc = seg ? 1.f : QSCALE;
#pragma unroll
        for (int rb = 0; rb < 2; ++rb)
#pragma unroll
            for (int cb = 0; cb < 2; ++cb) {
                int ngs = (bn & 511) + wr * 64 + rb * 32;   // n in segment (mult of 32)
                int m = bm + wc * 64 + cb * 32 + lo31;
                int b = m >> 11, l = m & (LL - 1);
                int h = ngs >> 6;
                size_t obase = (size_t)seg * 2097152 + (((size_t)(b * HH + h)) * LL + l) * DD;
#pragma unroll
                for (int g4 = 0; g4 < 4; ++g4) {
                    int nn = ngs + 8 * g4 + 4 * hi;
                    float4 bi = *(const float4*)&bs[nn];
                    uint2 u;
                    u.x = pk(sc * (acc[rb][cb][4 * g4 + 0] + bi.x),
                             sc * (acc[rb][cb][4 * g4 + 1] + bi.y));
                    u.y = pk(sc * (acc[rb][cb][4 * g4 + 2] + bi.z),
                             sc * (acc[rb][cb][4 * g4 + 3] + bi.w));
                    *(uint2*)&outb[obase + (nn & 63)] = u;
                }
            }
    } else {
#pragma unroll
        for (int rb = 0; rb < 2; ++rb)
#pragma unroll
            for (int cb = 0; cb < 2; ++cb) {
                int d = rb * 32 + lo31;
                int h = ((bn & 511) >> 6) + wr;
                int lbase = bm + wc * 64 + cb * 32;
                int b = lbase >> 11;
                float bi = bvv[(bn & 511) + wr * 64 + rb * 32 + lo31];
                size_t obase = (size_t)2 * 2097152 + (((size_t)(b * HH + h)) * DD + d) * LL;
#pragma unroll
                for (int g4 = 0; g4 < 4; ++g4) {
                    int l0 = (lbase + 8 * g4 + 4 * hi) & (LL - 1);
                    uint2 u;
                    u.x = pk(acc[rb][cb][4 * g4 + 0] + bi, acc[rb][cb][4 * g4 + 1] + bi);
                    u.y = pk(acc[rb][cb][4 * g4 + 2] + bi, acc[rb][cb][4 * g4 + 3] + bi);
                    *(uint2*)&outb[obase + l0] = u;
                }
            }
    }
}

// ---------------- MFMA GEMM (64x64): out = A @ W^T + bias (+resid) (+LN stats) --------
// Used for out-proj (K=512) and conv (K=256); N=256 -> 256 blocks. fp32 out only.
#define MLDK 68
__global__ __launch_bounds__(256) void k_mm(const unsigned short* __restrict__ A,
                                            const unsigned short* __restrict__ W,
                                            const float* __restrict__ b0,
                                            const float* resid,
                                            float* out,
                                            float* pstat,
                                            int M, int N, int K) {
    __shared__ unsigned short As[2][64][MLDK];
    __shared__ unsigned short Ws[2][64][MLDK];
    __shared__ float rs[4][2];
    int tid = threadIdx.x;
    int w = tid >> 6, lane = tid & 63, g = lane >> 4, qi = lane & 15;
    int bm = blockIdx.x * 64, bn = blockIdx.y * 64;
    int wr = w >> 1, wc = w & 1;
    int srow = tid >> 2, sq = tid & 3;
    f32x4 acc[2][2];
    acc[0][0] = acc[0][1] = acc[1][0] = acc[1][1] = (f32x4){0.f, 0.f, 0.f, 0.f};
    uint4 ra[2], rw[2];
#pragma unroll
    for (int p = 0; p < 2; ++p) {
        ra[p] = *(const uint4*)&A[(size_t)(bm + srow) * K + (sq + 4 * p) * 8];
        rw[p] = *(const uint4*)&W[(size_t)(bn + srow) * K + (sq + 4 * p) * 8];
    }
    int nt = K >> 6;
    for (int it = 0; it < nt; ++it) {
        int buf = it & 1;
#pragma unroll
        for (int p = 0; p < 2; ++p) {
            *(uint2*)&As[buf][srow][(sq + 4 * p) * 8]     = make_uint2(ra[p].x, ra[p].y);
            *(uint2*)&As[buf][srow][(sq + 4 * p) * 8 + 4] = make_uint2(ra[p].z, ra[p].w);
            *(uint2*)&Ws[buf][srow][(sq + 4 * p) * 8]     = make_uint2(rw[p].x, rw[p].y);
            *(uint2*)&Ws[buf][srow][(sq + 4 * p) * 8 + 4] = make_uint2(rw[p].z, rw[p].w);
        }
        __syncthreads();
        if (it + 1 < nt) {
            int k0 = (it + 1) << 6;
#pragma unroll
            for (int p = 0; p < 2; ++p) {
                ra[p] = *(const uint4*)&A[(size_t)(bm + srow) * K + k0 + (sq + 4 * p) * 8];
                rw[p] = *(const uint4*)&W[(size_t)(bn + srow) * K + k0 + (sq + 4 * p) * 8];
            }
        }
#pragma unroll
        for (int c = 0; c < 2; ++c) {
            short8 wf0 = ld_frag(&Ws[buf][wr * 32 + 0  + qi][c * 32 + 8 * g]);
            short8 wf1 = ld_frag(&Ws[buf][wr * 32 + 16 + qi][c * 32 + 8 * g]);
            short8 af0 = ld_frag(&As[buf][wc * 32 + 0  + qi][c * 32 + 8 * g]);
            short8 af1 = ld_frag(&As[buf][wc * 32 + 16 + qi][c * 32 + 8 * g]);
            acc[0][0] = __builtin_amdgcn_mfma_f32_16x16x32_bf16(wf0, af0, acc[0][0], 0, 0, 0);
            acc[0][1] = __builtin_amdgcn_mfma_f32_16x16x32_bf16(wf0, af1, acc[0][1], 0, 0, 0);
            acc[1][0] = __builtin_amdgcn_mfma_f32_16x16x32_bf16(wf1, af0, acc[1][0], 0, 0, 0);
            acc[1][1] = __builtin_amdgcn_mfma_f32_16x16x32_bf16(wf1, af1, acc[1][1], 0, 0, 0);
        }
    }
    float s = 0.f, s2 = 0.f;
#pragma unroll
    for (int fi = 0; fi < 2; ++fi)
#pragma unroll
        for (int fj = 0; fj < 2; ++fj) {
            int n0 = bn + wr * 32 + fi * 16 + 4 * g;
            int m  = bm + wc * 32 + fj * 16 + qi;
            float4 bi = *(const float4*)&b0[n0];
            float4 v;
            v.x = acc[fi][fj][0] + bi.x; v.y = acc[fi][fj][1] + bi.y;
            v.z = acc[fi][fj][2] + bi.z; v.w = acc[fi][fj][3] + bi.w;
            if (resid) {
                float4 rv = *(const float4*)&resid[(size_t)m * N + n0];
                v.x += rv.x; v.y += rv.y; v.z += rv.z; v.w += rv.w;
            }
            *(float4*)&out[(size_t)m * N + n0] = v;
            s  += (v.x + v.y) + (v.z + v.w);
            s2 += v.x * v.x + v.y * v.y + v.z * v.z + v.w * v.w;
        }
    if (pstat) {
        s = wred_sum(s); s2 = wred_sum(s2);
        if (lane == 0) { rs[w][0] = s; rs[w][1] = s2; }
        __syncthreads();
        if (tid == 0) {
            int bid = blockIdx.y * gridDim.x + blockIdx.x;
            pstat[bid * 2 + 0] = rs[0][0] + rs[1][0] + rs[2][0] + rs[3][0];
            pstat[bid * 2 + 1] = rs[0][1] + rs[1][1] + rs[2][1] + rs[3][1];
        }
    }
}

// ---------------- MFMA flash attention: 32x32 math + LDS staging + in-reg P ------------
// (r14 structure, verified: absmax 0.0625; best total 82.9us.)
#define LDK 68
__global__ __launch_bounds__(256) void k_attn(const unsigned short* __restrict__ QKV,
                                              unsigned short* __restrict__ op0,
                                              unsigned short* __restrict__ op1,
                                              float* __restrict__ ls) {
    int bh = blockIdx.x;               // b*8 + h  (XCD-pinned: id%8 = bh%8)
    int h = bh & 7, b = bh >> 3;
    int z = blockIdx.z;
    int sb0 = z << 10;                 // this block's s-range start (1024 keys, 16 tiles)
    int tid = threadIdx.x;
    int w = tid >> 6, lane = tid & 63;
    int lo31 = lane & 31, hi = lane >> 5;
    int q0 = blockIdx.y * 128 + w * 32;
    __shared__ unsigned short Ks[2][64][LDK];    // [s][d]
    __shared__ unsigned short Vts[2][64][LDK];   // [d][s]
    const unsigned short* Qg = QKV + (size_t)bh * LL * DD;
    const unsigned short* Kg = QKV + 2097152 + (size_t)bh * LL * DD;
    const unsigned short* Vg = QKV + (size_t)2 * 2097152 + (size_t)bh * DD * LL;

    short8 qf[4];
#pragma unroll
    for (int c = 0; c < 4; ++c)
        qf[c] = *(const short8*)&Qg[(size_t)(q0 + lo31) * DD + c * 16 + 8 * hi];

    f32x16 o0, o1;
#pragma unroll
    for (int r = 0; r < 16; ++r) { o0[r] = 0.f; o1[r] = 0.f; }
    float m = -INFINITY, sum = 0.f;

    int srow = tid >> 2, sq = tid & 3;
    uint4 kr[2], vr[2];
#pragma unroll
    for (int p = 0; p < 2; ++p) {
        kr[p] = *(const uint4*)&Kg[(size_t)(sb0 + srow) * DD + (sq + 4 * p) * 8];
        vr[p] = *(const uint4*)&Vg[(size_t)srow * LL + sb0 + (sq + 4 * p) * 8];
    }
    for (int it = 0; it < 16; ++it) {
        int buf = it & 1;
#pragma unroll
        for (int p = 0; p < 2; ++p) {
            *(uint2*)&Ks[buf][srow][(sq + 4 * p) * 8]      = make_uint2(kr[p].x, kr[p].y);
            *(uint2*)&Ks[buf][srow][(sq + 4 * p) * 8 + 4]  = make_uint2(kr[p].z, kr[p].w);
            *(uint2*)&Vts[buf][srow][(sq + 4 * p) * 8]     = make_uint2(vr[p].x, vr[p].y);
            *(uint2*)&Vts[buf][srow][(sq + 4 * p) * 8 + 4] = make_uint2(vr[p].z, vr[p].w);
        }
        __syncthreads();
        if (it + 1 < 16) {
            int s1 = sb0 + (it + 1) * 64;
#pragma unroll
            for (int p = 0; p < 2; ++p) {
                kr[p] = *(const uint4*)&Kg[(size_t)(s1 + srow) * DD + (sq + 4 * p) * 8];
                vr[p] = *(const uint4*)&Vg[(size_t)srow * LL + s1 + (sq + 4 * p) * 8];
            }
        }
#pragma unroll
        for (int sub = 0; sub < 2; ++sub) {
            f32x16 st;
#pragma unroll
            for (int r = 0; r < 16; ++r) st[r] = 0.f;
            __builtin_amdgcn_s_setprio(1);
#pragma unroll
            for (int c = 0; c < 4; ++c) {
                short8 kf = ld_frag(&Ks[buf][sub * 32 + lo31][c * 16 + 8 * hi]);
                st = __builtin_amdgcn_mfma_f32_32x32x16_bf16(kf, qf[c], st, 0, 0, 0);
            }
            __builtin_amdgcn_s_setprio(0);
            float t0 = fmaxf(fmaxf(st[0], st[1]),   fmaxf(st[2], st[3]));
            float t1 = fmaxf(fmaxf(st[4], st[5]),   fmaxf(st[6], st[7]));
            float t2 = fmaxf(fmaxf(st[8], st[9]),   fmaxf(st[10], st[11]));
            float t3 = fmaxf(fmaxf(st[12], st[13]), fmaxf(st[14], st[15]));
            float tmax = fmaxf(fmaxf(t0, t1), fmaxf(t2, t3));
            tmax = fmaxf(tmax, __shfl_xor(tmax, 32, 64));
            if (!__all(tmax - m <= 8.f)) {
                float mnew = fmaxf(m, tmax);
                float corr = ex2(m - mnew);
                m = mnew;
                sum *= corr;
#pragma unroll
                for (int r = 0; r < 16; ++r) { o0[r] *= corr; o1[r] *= corr; }
            }
            float p[16];
#pragma unroll
            for (int r = 0; r < 16; ++r) p[r] = ex2(st[r] - m);
            float sA = (p[0] + p[1])   + (p[2] + p[3]);
            float sB = (p[4] + p[5])   + (p[6] + p[7]);
            float sC = (p[8] + p[9])   + (p[10] + p[11]);
            float sD = (p[12] + p[13]) + (p[14] + p[15]);
            sum += (sA + sB) + (sC + sD);
            unsigned pa = pk(p[0], p[1]),   pb = pk(p[2], p[3]);
            unsigned pc = pk(p[4], p[5]),   pd = pk(p[6], p[7]);
            pswap(pc, pa); pswap(pd, pb);
            unsigned pe = pk(p[8], p[9]),   pf = pk(p[10], p[11]);
            unsigned pg = pk(p[12], p[13]), ph = pk(p[14], p[15]);
            pswap(pg, pe); pswap(ph, pf);
            short8 pb0 = mk8(pa, pb, pc, pd);
            short8 pb1 = mk8(pe, pf, pg, ph);
            __builtin_amdgcn_s_setprio(1);
            {
                short8 vf00 = ld_frag(&Vts[buf][lo31][sub * 32 + 8 * hi]);
                short8 vf01 = ld_frag(&Vts[buf][lo31][sub * 32 + 16 + 8 * hi]);
                short8 vf10 = ld_frag(&Vts[buf][32 + lo31][sub * 32 + 8 * hi]);
                short8 vf11 = ld_frag(&Vts[buf][32 + lo31][sub * 32 + 16 + 8 * hi]);
                o0 = __builtin_amdgcn_mfma_f32_32x32x16_bf16(vf00, pb0, o0, 0, 0, 0);
                o0 = __builtin_amdgcn_mfma_f32_32x32x16_bf16(vf01, pb1, o0, 0, 0, 0);
                o1 = __builtin_amdgcn_mfma_f32_32x32x16_bf16(vf10, pb0, o1, 0, 0, 0);
                o1 = __builtin_amdgcn_mfma_f32_32x32x16_bf16(vf11, pb1, o1, 0, 0, 0);
            }
            __builtin_amdgcn_s_setprio(0);
        }
    }
    sum += __shfl_xor(sum, 32, 64);
    float rinv = 1.f / sum;
    unsigned short* op = z ? op1 : op0;
    size_t base = ((size_t)(b * LL + q0 + lo31)) * HDIM + h * DD;
#pragma unroll
    for (int j = 0; j < 4; ++j) {
        int d0 = 8 * j + 4 * hi;
        uint2 u;
        u.x = pk(o0[4 * j + 0] * rinv, o0[4 * j + 1] * rinv);
        u.y = pk(o0[4 * j + 2] * rinv, o0[4 * j + 3] * rinv);
        *(uint2*)&op[base + d0] = u;
        uint2 u1;
        u1.x = pk(o1[4 * j + 0] * rinv, o1[4 * j + 1] * rinv);
        u1.y = pk(o1[4 * j + 2] * rinv, o1[4 * j + 3] * rinv);
        *(uint2*)&op[base + 32 + d0] = u1;
    }
    if (hi == 0) ls[(z << 15) + bh * LL + q0 + lo31] = m + lg2(sum);
}

// ---------------- merge of the 2 split-S partials (exact softmax combine, verified r13) --
__global__ __launch_bounds__(256) void k_amerge(const unsigned short* op0,
                                                const unsigned short* op1,
                                                const float* __restrict__ ls,
                                                unsigned short* out) {
    int flat = (blockIdx.x * 256 + threadIdx.x) * 8;
    int tt = flat >> 9;                   // token = b*LL + l
    int h  = (flat >> 6) & 7;
    int b  = tt >> 11, l = tt & (LL - 1);
    int bh = b * HH + h;
    float l0 = ls[bh * LL + l];
    float l1 = ls[(1 << 15) + bh * LL + l];
    float M  = fmaxf(l0, l1);
    float w0 = ex2(l0 - M), w1 = ex2(l1 - M);
    float inv = 1.f / (w0 + w1);
    w0 *= inv; w1 *= inv;
    uint4 a = *(const uint4*)&op0[flat];
    uint4 c = *(const uint4*)&op1[flat];
    const unsigned* au = (const unsigned*)&a;
    const unsigned* cu = (const unsigned*)&c;
    uint4 r;
    unsigned* ru = (unsigned*)&r;
#pragma unroll
    for (int i = 0; i < 4; ++i) {
        float a0 = bf2f((unsigned short)(au[i] & 0xffff));
        float a1 = bf2f((unsigned short)(au[i] >> 16));
        float c0 = bf2f((unsigned short)(cu[i] & 0xffff));
        float c1 = bf2f((unsigned short)(cu[i] >> 16));
        ru[i] = pk(w0 * a0 + w1 * c0, w0 * a1 + w1 * c1);
    }
    *(uint4*)&out[flat] = r;
}

// ---------------- LN apply, vectorized (+PReLU, +add, +bf16 copy, +out partials) ------
__global__ __launch_bounds__(256) void k_ln(const float* in,
                                            const float* __restrict__ g,
                                            const float* __restrict__ be,
                                            const float* __restrict__ pin,
                                            const float* __restrict__ add,
                                            const float* __restrict__ alpha_ptr,
                                            float* out, unsigned short* outb,
                                            float* pout) {
    __shared__ float rs[4][2];
    int tid = threadIdx.x;
    int b = blockIdx.x >> 9;           // 512 blocks per batch
    float s = 0.f, s2 = 0.f;
    if (tid < 128) {
        int pidx = (tid >> 5) * 64 + b * 32 + (tid & 31);
        s  = pin[pidx * 2 + 0];
        s2 = pin[pidx * 2 + 1];
    }
    s = wred_sum(s); s2 = wred_sum(s2);
    if ((tid & 63) == 0 && tid < 128) { rs[tid >> 6][0] = s; rs[tid >> 6][1] = s2; }
    __syncthreads();
    float S = rs[0][0] + rs[1][0], S2 = rs[0][1] + rs[1][1];
    float mean = S / (float)(CC * LL);
    float inv  = rsqrtf(S2 / (float)(CC * LL) - mean * mean + EPSV);

    int idx = (blockIdx.x * 256 + tid) * 4;
    int c = idx & (CC - 1);
    float4 v  = *(const float4*)&in[idx];
    float4 gg = *(const float4*)&g[c];
    float4 bb = *(const float4*)&be[c];
    v.x = (v.x - mean) * inv * gg.x + bb.x;
    v.y = (v.y - mean) * inv * gg.y + bb.y;
    v.z = (v.z - mean) * inv * gg.z + bb.z;
    v.w = (v.w - mean) * inv * gg.w + bb.w;
    if (alpha_ptr) {
        float al = alpha_ptr[0];
        v.x = v.x >= 0.f ? v.x : al * v.x;
        v.y = v.y >= 0.f ? v.y : al * v.y;
        v.z = v.z >= 0.f ? v.z : al * v.z;
        v.w = v.w >= 0.f ? v.w : al * v.w;
    }
    if (add) {
        float4 a = *(const float4*)&add[idx];
        v.x += a.x; v.y += a.y; v.z += a.z; v.w += a.w;
    }
    *(float4*)&out[idx] = v;
    if (outb) {
        uint2 u; u.x = pk(v.x, v.y); u.y = pk(v.z, v.w);
        *(uint2*)&outb[idx] = u;
    }
    if (pout) {
        float os  = (v.x + v.y) + (v.z + v.w);
        float os2 = v.x * v.x + v.y * v.y + v.z * v.z + v.w * v.w;
        os = wred_sum(os); os2 = wred_sum(os2);
        __syncthreads();   // rs reuse
        if ((tid & 63) == 0) { rs[tid >> 6][0] = os; rs[tid >> 6][1] = os2; }
        __syncthreads();
        if (tid == 0) {
            pout[blockIdx.x * 2 + 0] = rs[0][0] + rs[1][0] + rs[2][0] + rs[3][0];
            pout[blockIdx.x * 2 + 1] = rs[0][1] + rs[1][1] + rs[2][1] + rs[3][1];
        }
    }
}

// ---------------- final LN + transpose out (B,L,C) -> (B,C,L) ----------------
__global__ __launch_bounds__(256) void k_ln_t(const float* __restrict__ in,
                                              const float* __restrict__ g,
                                              const float* __restrict__ be,
                                              const float* __restrict__ pin,
                                              float* __restrict__ out) {
    __shared__ float tr[64][65];   // [c][l]
    __shared__ float rs[4][2];
    int l0 = blockIdx.x * 64, c0 = blockIdx.y * 64, b = blockIdx.z;
    int tid = threadIdx.x, r = tid >> 2, q = tid & 3;
    float s  = pin[(b * 512 + tid) * 2 + 0] + pin[(b * 512 + 256 + tid) * 2 + 0];
    float s2 = pin[(b * 512 + tid) * 2 + 1] + pin[(b * 512 + 256 + tid) * 2 + 1];
    s = wred_sum(s); s2 = wred_sum(s2);
    if ((tid & 63) == 0) { rs[tid >> 6][0] = s; rs[tid >> 6][1] = s2; }
    __syncthreads();
    float S = rs[0][0] + rs[1][0] + rs[2][0] + rs[3][0];
    float S2 = rs[0][1] + rs[1][1] + rs[2][1] + rs[3][1];
    float mean = S / (float)(CC * LL);
    float inv  = rsqrtf(S2 / (float)(CC * LL) - mean * mean + EPSV);
#pragma unroll
    for (int p = 0; p < 4; ++p) {
        int cc = 4 * (q + 4 * p);
        float4 v  = *(const float4*)&in[((size_t)(b * LL + l0 + r)) * CC + c0 + cc];
        float4 gg = *(const float4*)&g[c0 + cc];
        float4 bb = *(const float4*)&be[c0 + cc];
        tr[cc + 0][r] = (v.x - mean) * inv * gg.x + bb.x;
        tr[cc + 1][r] = (v.y - mean) * inv * gg.y + bb.y;
        tr[cc + 2][r] = (v.z - mean) * inv * gg.z + bb.z;
        tr[cc + 3][r] = (v.w - mean) * inv * gg.w + bb.w;
    }
    __syncthreads();
#pragma unroll
    for (int p = 0; p < 4; ++p) {
        int ll = 4 * (q + 4 * p);
        float4 v = *(const float4*)&tr[r][ll];
        *(float4*)&out[((size_t)(b * CC + c0 + r)) * LL + l0 + ll] = v;
    }
}

// ---------------- launch ----------------
extern "C" void kernel_launch(void* const* d_in, const int* in_sizes, int n_in,
                              void* d_out, int out_size, void* d_ws, size_t ws_size,
                              hipStream_t stream) {
    const float* x      = (const float*)d_in[0];
    const float* Wq     = (const float*)d_in[1];
    const float* bq     = (const float*)d_in[2];
    const float* Wk     = (const float*)d_in[3];
    const float* bk     = (const float*)d_in[4];
    const float* Wv     = (const float*)d_in[5];
    const float* bv     = (const float*)d_in[6];
    const float* Wo     = (const float*)d_in[7];
    const float* bo     = (const float*)d_in[8];
    const float* g_mha  = (const float*)d_in[9];
    const float* b_mha  = (const float*)d_in[10];
    const float* conv_w = (const float*)d_in[11];
    const float* conv_b = (const float*)d_in[12];
    const float* g_ffn  = (const float*)d_in[13];
    const float* b_ffn  = (const float*)d_in[14];
    const float* alpha  = (const float*)d_in[15];
    const float* g_out  = (const float*)d_in[16];
    const float* b_out  = (const float*)d_in[17];
    float* out = (float*)d_out;

    // workspace layout (float units)
    float* ws = (float*)d_ws;
    float* t             = ws;                               // [0, 1,048,576)
    unsigned short* tb   = (unsigned short*)(ws + 1048576);  // [1,048,576, 1,572,864)
    unsigned short* QKVb = (unsigned short*)(ws + 1572864);  // [1,572,864, 4,718,592) 3x2M bf16
    float* f             = ws + 1572864;                     // reuse QKV (dead after attn)
    unsigned short* ybf  = (unsigned short*)(ws + 2621440);  // reuse QKV (dead after attn)
    unsigned short* obuf = (unsigned short*)(ws + 4718592);  // [4,718,592, 5,767,168) op0
    unsigned short* Wqkvb= (unsigned short*)(ws + 5767168);  // 393216 bf16
    unsigned short* Wob  = (unsigned short*)(ws + 5963776);  // 131072 bf16
    unsigned short* Wcb  = (unsigned short*)(ws + 6029312);  // 65536 bf16
    float* pstatA        = ws + 6062080;                     // 512 f
    float* pstatB        = ws + 6062592;                     // 512 f
    float* pstatC        = ws + 6063104;                     // 2048 f
    unsigned short* op1  = (unsigned short*)(ws + 6065152);  // 2M bf16 = 1,048,576 f
    float* lsbuf         = ws + 7113728;                     // 65,536 f  (2 x 16 x 2048)

    k_prep<<<832, 256, 0, stream>>>(x, Wq, Wk, Wv, Wo, conv_w, t, tb, Wqkvb, Wob, Wcb);

    dim3 gqkv(BLQ / 128, 1536 / 128);        // 32,12 — 128^2 tile, 32x32 MFMA
    k_mmq<<<gqkv, 256, 0, stream>>>(tb, Wqkvb, bq, bk, bv, QKVb);

    dim3 gattn(HH * BB, LL / 128, 2);        // (16 bh, 16 qt, 2 s-halves) = 512 blocks
    k_attn<<<gattn, 256, 0, stream>>>(QKVb, obuf, op1, lsbuf);
    k_amerge<<<1024, 256, 0, stream>>>(obuf, op1, lsbuf, obuf);

    dim3 go(BLQ / 64, CC / 64);              // 64,4
    k_mm<<<go, 256, 0, stream>>>(obuf, Wob, bo, t, t, pstatA, BLQ, CC, HDIM);

    k_ln<<<1024, 256, 0, stream>>>(t, g_mha, b_mha, pstatA, nullptr, nullptr,
                                   t, ybf, nullptr);             // y := ln(t), + bf16

    k_mm<<<go, 256, 0, stream>>>(ybf, Wcb, conv_b, nullptr, f, pstatB, BLQ, CC, CC);

    k_ln<<<1024, 256, 0, stream>>>(f, g_ffn, b_ffn, pstatB, t, alpha,
                                   f, nullptr, pstatC);          // f := prelu(ln(f)) + y, stats

    k_ln_t<<<dim3(LL / 64, CC / 64, BB), 256, 0, stream>>>(f, g_out, b_out, pstatC, out);
}

// Round 18
// 83.754 us; speedup vs baseline: 1.0792x; 1.0792x over previous
//
#include <hip/hip_runtime.h>
#include <hip/hip_bf16.h>
#include <math.h>

// Problem constants
#define BB   2
#define CC   256
#define LL   2048
#define DD   64
#define HH   8
#define HDIM 512
#define BLQ  (BB*LL)      // 4096 tokens
#define EPSV 1e-8f
#define QSCALE (0.125f * 1.44269504088896f)   // 1/sqrt(64) * log2(e): softmax in exp2 domain

typedef __attribute__((ext_vector_type(8))) short short8;    // 8 bf16 (4 VGPRs)
typedef __attribute__((ext_vector_type(4))) float f32x4;     // 16x16 MFMA acc
typedef __attribute__((ext_vector_type(16))) float f32x16;   // 32x32 MFMA acc

// ---------------- helpers ----------------
__device__ __forceinline__ float wred_sum(float v) {
#pragma unroll
    for (int off = 32; off > 0; off >>= 1) v += __shfl_down(v, off, 64);
    return v;
}
// HW packed fp32x2 -> bf16x2 (RNE), single v_cvt_pk_bf16_f32
__device__ __forceinline__ unsigned pk(float a, float b) {
    unsigned r;
    asm("v_cvt_pk_bf16_f32 %0, %1, %2" : "=v"(r) : "v"(a), "v"(b));
    return r;
}
// bare HW exp2 / log2 (softmax runs in the exp2 domain; libm paths are multi-instr)
__device__ __forceinline__ float ex2(float x) {
    float r;
    asm("v_exp_f32 %0, %1" : "=v"(r) : "v"(x));
    return r;
}
__device__ __forceinline__ float lg2(float x) {
    float r;
    asm("v_log_f32 %0, %1" : "=v"(r) : "v"(x));
    return r;
}
__device__ __forceinline__ float bf2f(unsigned short v) {
    union { unsigned u; float f; } c; c.u = ((unsigned)v) << 16; return c.f;
}
// cross-half register swap: x[0:31] <-> y[32:63]  (v_permlane32_swap_b32; verified r6)
__device__ __forceinline__ void pswap(unsigned &x, unsigned &y) {
    asm("v_permlane32_swap_b32 %0, %1" : "+v"(x), "+v"(y));
}
__device__ __forceinline__ short8 mk8(unsigned x0, unsigned x1, unsigned x2, unsigned x3) {
    union { short8 v; unsigned u[4]; } r;
    r.u[0] = x0; r.u[1] = x1; r.u[2] = x2; r.u[3] = x3;
    return r.v;
}
// assemble a bf16x8 fragment from two 8B LDS loads (stride-68, measured-low-conflict)
__device__ __forceinline__ short8 ld_frag(const unsigned short* p) {
    union { short8 v; uint2 u[2]; } f;
    f.u[0] = *(const uint2*)p;
    f.u[1] = *(const uint2*)(p + 4);
    return f.v;
}

// ---------------- prep (fused): t = x^T + PE  AND  weight fp32->bf16 convert ----------
__global__ __launch_bounds__(256) void k_prep(const float* __restrict__ x,
                                              const float* __restrict__ Wq, const float* __restrict__ Wk,
                                              const float* __restrict__ Wv, const float* __restrict__ Wo,
                                              const float* __restrict__ Wc,
                                              float* __restrict__ t,
                                              unsigned short* __restrict__ tb,
                                              unsigned short* __restrict__ dqkv,
                                              unsigned short* __restrict__ dWo,
                                              unsigned short* __restrict__ dWc) {
    int bid = blockIdx.x;
    int tid = threadIdx.x;
    if (bid >= 256) {   // ---- weight convert: 576 blocks * 256 thr * 4 elems ----
        int idx = ((bid - 256) * 256 + tid) * 4;
        const float* s; unsigned short* d;
        if (idx < 131072)      { s = Wq + idx;          d = dqkv + idx; }
        else if (idx < 262144) { s = Wk + idx - 131072; d = dqkv + idx; }
        else if (idx < 393216) { s = Wv + idx - 262144; d = dqkv + idx; }
        else if (idx < 524288) { s = Wo + idx - 393216; d = dWo + idx - 393216; }
        else                   { s = Wc + idx - 524288; d = dWc + idx - 524288; }
        float4 v = *(const float4*)s;
        uint2 u; u.x = pk(v.x, v.y); u.y = pk(v.z, v.w);
        *(uint2*)d = u;
        return;
    }
    // ---- transpose + positional encoding ----
    __shared__ float tr[64][65];    // [l][c]
    int l0 = (bid & 31) * 64, c0 = ((bid >> 5) & 3) * 64, b = bid >> 7;
    int r = tid >> 2, q = tid & 3;
#pragma unroll
    for (int p = 0; p < 4; ++p) {
        int lc = 4 * (q + 4 * p);
        float4 v = *(const float4*)&x[((size_t)(b * CC + c0 + r)) * LL + l0 + lc];
        tr[lc + 0][r] = v.x; tr[lc + 1][r] = v.y; tr[lc + 2][r] = v.z; tr[lc + 3][r] = v.w;
    }
    __syncthreads();
    int lg = l0 + r;
#pragma unroll
    for (int p = 0; p < 4; ++p) {
        int cc = 4 * (q + 4 * p);
        float4 v = *(const float4*)&tr[r][cc];
        float pe[4];
#pragma unroll
        for (int i = 0; i < 4; ++i) {
            int cg = c0 + cc + i;
            float freq = __expf((float)(cg & ~1) * (-9.210340371976184f / (float)CC));
            float ang = (float)lg * freq;
            pe[i] = (cg & 1) ? __cosf(ang) : __sinf(ang);
        }
        v.x += pe[0]; v.y += pe[1]; v.z += pe[2]; v.w += pe[3];
        size_t o = ((size_t)(b * LL + lg)) * CC + c0 + cc;
        *(float4*)&t[o] = v;
        uint2 u; u.x = pk(v.x, v.y); u.y = pk(v.z, v.w);
        *(uint2*)&tb[o] = u;
    }
}

// ---------------- MFMA GEMM: out = A @ W^T (+bias) (+resid) (+partial LN stats) --------
// mode 0: fp32 out, bias b0, optional resid (may alias out), optional pstat.
// mode 1: QKV epilogue (Q/K (B,H,L,D) bf16, V transposed (B,H,D,L) bf16).
// r15 lesson: no extra work in the A-staging path (barrier-exposed).
// r17 lesson: 128^2 tile with K<=256 regressed (short K can't amortize); keep 64^2.
#define MLDK 68
__global__ __launch_bounds__(256) void k_mm(const unsigned short* __restrict__ A,
                                            const unsigned short* __restrict__ W,
                                            const float* __restrict__ b0,
                                            const float* __restrict__ b1,
                                            const float* __restrict__ b2,
                                            const float* resid,
                                            float* out, unsigned short* outb,
                                            float* pstat,
                                            int mode, int M, int N, int K) {
    __shared__ unsigned short As[2][64][MLDK];
    __shared__ unsigned short Ws[2][64][MLDK];
    __shared__ float rs[4][2];
    int tid = threadIdx.x;
    int w = tid >> 6, lane = tid & 63, g = lane >> 4, qi = lane & 15;
    int bm = blockIdx.x * 64, bn = blockIdx.y * 64;
    int wr = w >> 1, wc = w & 1;
    int srow = tid >> 2, sq = tid & 3;
    bool vseg = (mode == 1) && (bn >= 1024);
    f32x4 acc[2][2];
    acc[0][0] = acc[0][1] = acc[1][0] = acc[1][1] = (f32x4){0.f, 0.f, 0.f, 0.f};
    uint4 ra[2], rw[2];
#pragma unroll
    for (int p = 0; p < 2; ++p) {
        ra[p] = *(const uint4*)&A[(size_t)(bm + srow) * K + (sq + 4 * p) * 8];
        rw[p] = *(const uint4*)&W[(size_t)(bn + srow) * K + (sq + 4 * p) * 8];
    }
    int nt = K >> 6;
    for (int it = 0; it < nt; ++it) {
        int buf = it & 1;
#pragma unroll
        for (int p = 0; p < 2; ++p) {
            *(uint2*)&As[buf][srow][(sq + 4 * p) * 8]     = make_uint2(ra[p].x, ra[p].y);
            *(uint2*)&As[buf][srow][(sq + 4 * p) * 8 + 4] = make_uint2(ra[p].z, ra[p].w);
            *(uint2*)&Ws[buf][srow][(sq + 4 * p) * 8]     = make_uint2(rw[p].x, rw[p].y);
            *(uint2*)&Ws[buf][srow][(sq + 4 * p) * 8 + 4] = make_uint2(rw[p].z, rw[p].w);
        }
        __syncthreads();
        if (it + 1 < nt) {
            int k0 = (it + 1) << 6;
#pragma unroll
            for (int p = 0; p < 2; ++p) {
                ra[p] = *(const uint4*)&A[(size_t)(bm + srow) * K + k0 + (sq + 4 * p) * 8];
                rw[p] = *(const uint4*)&W[(size_t)(bn + srow) * K + k0 + (sq + 4 * p) * 8];
            }
        }
#pragma unroll
        for (int c = 0; c < 2; ++c) {
            short8 wf0 = ld_frag(&Ws[buf][wr * 32 + 0  + qi][c * 32 + 8 * g]);
            short8 wf1 = ld_frag(&Ws[buf][wr * 32 + 16 + qi][c * 32 + 8 * g]);
            short8 af0 = ld_frag(&As[buf][wc * 32 + 0  + qi][c * 32 + 8 * g]);
            short8 af1 = ld_frag(&As[buf][wc * 32 + 16 + qi][c * 32 + 8 * g]);
            if (!vseg) {
                acc[0][0] = __builtin_amdgcn_mfma_f32_16x16x32_bf16(wf0, af0, acc[0][0], 0, 0, 0);
                acc[0][1] = __builtin_amdgcn_mfma_f32_16x16x32_bf16(wf0, af1, acc[0][1], 0, 0, 0);
                acc[1][0] = __builtin_amdgcn_mfma_f32_16x16x32_bf16(wf1, af0, acc[1][0], 0, 0, 0);
                acc[1][1] = __builtin_amdgcn_mfma_f32_16x16x32_bf16(wf1, af1, acc[1][1], 0, 0, 0);
            } else {
                acc[0][0] = __builtin_amdgcn_mfma_f32_16x16x32_bf16(af0, wf0, acc[0][0], 0, 0, 0);
                acc[0][1] = __builtin_amdgcn_mfma_f32_16x16x32_bf16(af0, wf1, acc[0][1], 0, 0, 0);
                acc[1][0] = __builtin_amdgcn_mfma_f32_16x16x32_bf16(af1, wf0, acc[1][0], 0, 0, 0);
                acc[1][1] = __builtin_amdgcn_mfma_f32_16x16x32_bf16(af1, wf1, acc[1][1], 0, 0, 0);
            }
        }
    }
    if (mode == 0) {
        float s = 0.f, s2 = 0.f;
#pragma unroll
        for (int fi = 0; fi < 2; ++fi)
#pragma unroll
            for (int fj = 0; fj < 2; ++fj) {
                int n0 = bn + wr * 32 + fi * 16 + 4 * g;
                int m  = bm + wc * 32 + fj * 16 + qi;
                float4 bi = *(const float4*)&b0[n0];
                float4 v;
                v.x = acc[fi][fj][0] + bi.x; v.y = acc[fi][fj][1] + bi.y;
                v.z = acc[fi][fj][2] + bi.z; v.w = acc[fi][fj][3] + bi.w;
                if (resid) {
                    float4 rv = *(const float4*)&resid[(size_t)m * N + n0];
                    v.x += rv.x; v.y += rv.y; v.z += rv.z; v.w += rv.w;
                }
                *(float4*)&out[(size_t)m * N + n0] = v;
                s  += (v.x + v.y) + (v.z + v.w);
                s2 += v.x * v.x + v.y * v.y + v.z * v.z + v.w * v.w;
            }
        if (pstat) {
            s = wred_sum(s); s2 = wred_sum(s2);
            if (lane == 0) { rs[w][0] = s; rs[w][1] = s2; }
            __syncthreads();
            if (tid == 0) {
                int bid = blockIdx.y * gridDim.x + blockIdx.x;
                pstat[bid * 2 + 0] = rs[0][0] + rs[1][0] + rs[2][0] + rs[3][0];
                pstat[bid * 2 + 1] = rs[0][1] + rs[1][1] + rs[2][1] + rs[3][1];
            }
        }
    } else if (!vseg) {
        int seg = bn >> 9;                      // 0 = Q, 1 = K
        const float* bs = seg ? b1 : b0;
        float sc = seg ? 1.f : QSCALE;
#pragma unroll
        for (int fi = 0; fi < 2; ++fi)
#pragma unroll
            for (int fj = 0; fj < 2; ++fj) {
                int nn0 = (bn & 511) + wr * 32 + fi * 16 + 4 * g;
                int m   = bm + wc * 32 + fj * 16 + qi;
                int b = m >> 11, l = m & (LL - 1);
                int h = nn0 >> 6, d0 = nn0 & 63;
                float4 bi = *(const float4*)&bs[nn0];
                uint2 u;
                u.x = pk(sc * (acc[fi][fj][0] + bi.x), sc * (acc[fi][fj][1] + bi.y));
                u.y = pk(sc * (acc[fi][fj][2] + bi.z), sc * (acc[fi][fj][3] + bi.w));
                *(uint2*)&outb[(size_t)seg * 2097152 +
                               (((size_t)(b * HH + h)) * LL + l) * DD + d0] = u;
            }
    } else {
#pragma unroll
        for (int fi = 0; fi < 2; ++fi)
#pragma unroll
            for (int fj = 0; fj < 2; ++fj) {
                int m0 = bm + wc * 32 + fi * 16 + 4 * g;
                int nn = (bn & 511) + wr * 32 + fj * 16 + qi;
                int b = m0 >> 11, l0 = m0 & (LL - 1);
                int h = nn >> 6, d = nn & 63;
                float bi = b2[nn];
                uint2 u;
                u.x = pk(acc[fi][fj][0] + bi, acc[fi][fj][1] + bi);
                u.y = pk(acc[fi][fj][2] + bi, acc[fi][fj][3] + bi);
                *(uint2*)&outb[(size_t)2 * 2097152 +
                               (((size_t)(b * HH + h)) * DD + d) * LL + l0] = u;
            }
    }
}

// ---------------- MFMA flash attention: 32x32 math + LDS staging + in-reg P ------------
// (r14 structure, verified: absmax 0.0625; best total 82.9us.) Block = 4 waves x 32 q;
// K-tiles of 64 staged in LDS (stride-68 b64), z=2 split-S; P packed in-register via
// cvt_pk+permlane32_swap; denominator in 4 parallel chains.
#define LDK 68
__global__ __launch_bounds__(256) void k_attn(const unsigned short* __restrict__ QKV,
                                              unsigned short* __restrict__ op0,
                                              unsigned short* __restrict__ op1,
                                              float* __restrict__ ls) {
    int bh = blockIdx.x;               // b*8 + h  (XCD-pinned: id%8 = bh%8)
    int h = bh & 7, b = bh >> 3;
    int z = blockIdx.z;
    int sb0 = z << 10;                 // this block's s-range start (1024 keys, 16 tiles)
    int tid = threadIdx.x;
    int w = tid >> 6, lane = tid & 63;
    int lo31 = lane & 31, hi = lane >> 5;
    int q0 = blockIdx.y * 128 + w * 32;
    __shared__ unsigned short Ks[2][64][LDK];    // [s][d]
    __shared__ unsigned short Vts[2][64][LDK];   // [d][s]
    const unsigned short* Qg = QKV + (size_t)bh * LL * DD;
    const unsigned short* Kg = QKV + 2097152 + (size_t)bh * LL * DD;
    const unsigned short* Vg = QKV + (size_t)2 * 2097152 + (size_t)bh * DD * LL;

    short8 qf[4];
#pragma unroll
    for (int c = 0; c < 4; ++c)
        qf[c] = *(const short8*)&Qg[(size_t)(q0 + lo31) * DD + c * 16 + 8 * hi];

    f32x16 o0, o1;
#pragma unroll
    for (int r = 0; r < 16; ++r) { o0[r] = 0.f; o1[r] = 0.f; }
    float m = -INFINITY, sum = 0.f;

    int srow = tid >> 2, sq = tid & 3;
    uint4 kr[2], vr[2];
#pragma unroll
    for (int p = 0; p < 2; ++p) {
        kr[p] = *(const uint4*)&Kg[(size_t)(sb0 + srow) * DD + (sq + 4 * p) * 8];
        vr[p] = *(const uint4*)&Vg[(size_t)srow * LL + sb0 + (sq + 4 * p) * 8];
    }
    for (int it = 0; it < 16; ++it) {
        int buf = it & 1;
#pragma unroll
        for (int p = 0; p < 2; ++p) {
            *(uint2*)&Ks[buf][srow][(sq + 4 * p) * 8]      = make_uint2(kr[p].x, kr[p].y);
            *(uint2*)&Ks[buf][srow][(sq + 4 * p) * 8 + 4]  = make_uint2(kr[p].z, kr[p].w);
            *(uint2*)&Vts[buf][srow][(sq + 4 * p) * 8]     = make_uint2(vr[p].x, vr[p].y);
            *(uint2*)&Vts[buf][srow][(sq + 4 * p) * 8 + 4] = make_uint2(vr[p].z, vr[p].w);
        }
        __syncthreads();
        if (it + 1 < 16) {
            int s1 = sb0 + (it + 1) * 64;
#pragma unroll
            for (int p = 0; p < 2; ++p) {
                kr[p] = *(const uint4*)&Kg[(size_t)(s1 + srow) * DD + (sq + 4 * p) * 8];
                vr[p] = *(const uint4*)&Vg[(size_t)srow * LL + s1 + (sq + 4 * p) * 8];
            }
        }
#pragma unroll
        for (int sub = 0; sub < 2; ++sub) {
            f32x16 st;
#pragma unroll
            for (int r = 0; r < 16; ++r) st[r] = 0.f;
            __builtin_amdgcn_s_setprio(1);
#pragma unroll
            for (int c = 0; c < 4; ++c) {
                short8 kf = ld_frag(&Ks[buf][sub * 32 + lo31][c * 16 + 8 * hi]);
                st = __builtin_amdgcn_mfma_f32_32x32x16_bf16(kf, qf[c], st, 0, 0, 0);
            }
            __builtin_amdgcn_s_setprio(0);
            float t0 = fmaxf(fmaxf(st[0], st[1]),   fmaxf(st[2], st[3]));
            float t1 = fmaxf(fmaxf(st[4], st[5]),   fmaxf(st[6], st[7]));
            float t2 = fmaxf(fmaxf(st[8], st[9]),   fmaxf(st[10], st[11]));
            float t3 = fmaxf(fmaxf(st[12], st[13]), fmaxf(st[14], st[15]));
            float tmax = fmaxf(fmaxf(t0, t1), fmaxf(t2, t3));
            tmax = fmaxf(tmax, __shfl_xor(tmax, 32, 64));
            if (!__all(tmax - m <= 8.f)) {
                float mnew = fmaxf(m, tmax);
                float corr = ex2(m - mnew);
                m = mnew;
                sum *= corr;
#pragma unroll
                for (int r = 0; r < 16; ++r) { o0[r] *= corr; o1[r] *= corr; }
            }
            float p[16];
#pragma unroll
            for (int r = 0; r < 16; ++r) p[r] = ex2(st[r] - m);
            float sA = (p[0] + p[1])   + (p[2] + p[3]);
            float sB = (p[4] + p[5])   + (p[6] + p[7]);
            float sC = (p[8] + p[9])   + (p[10] + p[11]);
            float sD = (p[12] + p[13]) + (p[14] + p[15]);
            sum += (sA + sB) + (sC + sD);
            unsigned pa = pk(p[0], p[1]),   pb = pk(p[2], p[3]);
            unsigned pc = pk(p[4], p[5]),   pd = pk(p[6], p[7]);
            pswap(pc, pa); pswap(pd, pb);
            unsigned pe = pk(p[8], p[9]),   pf = pk(p[10], p[11]);
            unsigned pg = pk(p[12], p[13]), ph = pk(p[14], p[15]);
            pswap(pg, pe); pswap(ph, pf);
            short8 pb0 = mk8(pa, pb, pc, pd);
            short8 pb1 = mk8(pe, pf, pg, ph);
            __builtin_amdgcn_s_setprio(1);
            {
                short8 vf00 = ld_frag(&Vts[buf][lo31][sub * 32 + 8 * hi]);
                short8 vf01 = ld_frag(&Vts[buf][lo31][sub * 32 + 16 + 8 * hi]);
                short8 vf10 = ld_frag(&Vts[buf][32 + lo31][sub * 32 + 8 * hi]);
                short8 vf11 = ld_frag(&Vts[buf][32 + lo31][sub * 32 + 16 + 8 * hi]);
                o0 = __builtin_amdgcn_mfma_f32_32x32x16_bf16(vf00, pb0, o0, 0, 0, 0);
                o0 = __builtin_amdgcn_mfma_f32_32x32x16_bf16(vf01, pb1, o0, 0, 0, 0);
                o1 = __builtin_amdgcn_mfma_f32_32x32x16_bf16(vf10, pb0, o1, 0, 0, 0);
                o1 = __builtin_amdgcn_mfma_f32_32x32x16_bf16(vf11, pb1, o1, 0, 0, 0);
            }
            __builtin_amdgcn_s_setprio(0);
        }
    }
    sum += __shfl_xor(sum, 32, 64);
    float rinv = 1.f / sum;
    unsigned short* op = z ? op1 : op0;
    size_t base = ((size_t)(b * LL + q0 + lo31)) * HDIM + h * DD;
#pragma unroll
    for (int j = 0; j < 4; ++j) {
        int d0 = 8 * j + 4 * hi;
        uint2 u;
        u.x = pk(o0[4 * j + 0] * rinv, o0[4 * j + 1] * rinv);
        u.y = pk(o0[4 * j + 2] * rinv, o0[4 * j + 3] * rinv);
        *(uint2*)&op[base + d0] = u;
        uint2 u1;
        u1.x = pk(o1[4 * j + 0] * rinv, o1[4 * j + 1] * rinv);
        u1.y = pk(o1[4 * j + 2] * rinv, o1[4 * j + 3] * rinv);
        *(uint2*)&op[base + 32 + d0] = u1;
    }
    if (hi == 0) ls[(z << 15) + bh * LL + q0 + lo31] = m + lg2(sum);
}

// ---------------- merge of the 2 split-S partials (exact softmax combine, verified r13) --
// Standalone kernel (1.7us at memory speed). r15: fusing into GEMM staging cost ~5us.
__global__ __launch_bounds__(256) void k_amerge(const unsigned short* op0,
                                                const unsigned short* op1,
                                                const float* __restrict__ ls,
                                                unsigned short* out) {
    int flat = (blockIdx.x * 256 + threadIdx.x) * 8;
    int tt = flat >> 9;                   // token = b*LL + l
    int h  = (flat >> 6) & 7;
    int b  = tt >> 11, l = tt & (LL - 1);
    int bh = b * HH + h;
    float l0 = ls[bh * LL + l];
    float l1 = ls[(1 << 15) + bh * LL + l];
    float M  = fmaxf(l0, l1);
    float w0 = ex2(l0 - M), w1 = ex2(l1 - M);
    float inv = 1.f / (w0 + w1);
    w0 *= inv; w1 *= inv;
    uint4 a = *(const uint4*)&op0[flat];
    uint4 c = *(const uint4*)&op1[flat];
    const unsigned* au = (const unsigned*)&a;
    const unsigned* cu = (const unsigned*)&c;
    uint4 r;
    unsigned* ru = (unsigned*)&r;
#pragma unroll
    for (int i = 0; i < 4; ++i) {
        float a0 = bf2f((unsigned short)(au[i] & 0xffff));
        float a1 = bf2f((unsigned short)(au[i] >> 16));
        float c0 = bf2f((unsigned short)(cu[i] & 0xffff));
        float c1 = bf2f((unsigned short)(cu[i] >> 16));
        ru[i] = pk(w0 * a0 + w1 * c0, w0 * a1 + w1 * c1);
    }
    *(uint4*)&out[flat] = r;
}

// ---------------- LN apply, vectorized (+PReLU, +add, +bf16 copy, +out partials) ------
__global__ __launch_bounds__(256) void k_ln(const float* in,
                                            const float* __restrict__ g,
                                            const float* __restrict__ be,
                                            const float* __restrict__ pin,
                                            const float* __restrict__ add,
                                            const float* __restrict__ alpha_ptr,
                                            float* out, unsigned short* outb,
                                            float* pout) {
    __shared__ float rs[4][2];
    int tid = threadIdx.x;
    int b = blockIdx.x >> 9;           // 512 blocks per batch
    float s = 0.f, s2 = 0.f;
    if (tid < 128) {
        int pidx = (tid >> 5) * 64 + b * 32 + (tid & 31);
        s  = pin[pidx * 2 + 0];
        s2 = pin[pidx * 2 + 1];
    }
    s = wred_sum(s); s2 = wred_sum(s2);
    if ((tid & 63) == 0 && tid < 128) { rs[tid >> 6][0] = s; rs[tid >> 6][1] = s2; }
    __syncthreads();
    float S = rs[0][0] + rs[1][0], S2 = rs[0][1] + rs[1][1];
    float mean = S / (float)(CC * LL);
    float inv  = rsqrtf(S2 / (float)(CC * LL) - mean * mean + EPSV);

    int idx = (blockIdx.x * 256 + tid) * 4;
    int c = idx & (CC - 1);
    float4 v  = *(const float4*)&in[idx];
    float4 gg = *(const float4*)&g[c];
    float4 bb = *(const float4*)&be[c];
    v.x = (v.x - mean) * inv * gg.x + bb.x;
    v.y = (v.y - mean) * inv * gg.y + bb.y;
    v.z = (v.z - mean) * inv * gg.z + bb.z;
    v.w = (v.w - mean) * inv * gg.w + bb.w;
    if (alpha_ptr) {
        float al = alpha_ptr[0];
        v.x = v.x >= 0.f ? v.x : al * v.x;
        v.y = v.y >= 0.f ? v.y : al * v.y;
        v.z = v.z >= 0.f ? v.z : al * v.z;
        v.w = v.w >= 0.f ? v.w : al * v.w;
    }
    if (add) {
        float4 a = *(const float4*)&add[idx];
        v.x += a.x; v.y += a.y; v.z += a.z; v.w += a.w;
    }
    *(float4*)&out[idx] = v;
    if (outb) {
        uint2 u; u.x = pk(v.x, v.y); u.y = pk(v.z, v.w);
        *(uint2*)&outb[idx] = u;
    }
    if (pout) {
        float os  = (v.x + v.y) + (v.z + v.w);
        float os2 = v.x * v.x + v.y * v.y + v.z * v.z + v.w * v.w;
        os = wred_sum(os); os2 = wred_sum(os2);
        __syncthreads();   // rs reuse
        if ((tid & 63) == 0) { rs[tid >> 6][0] = os; rs[tid >> 6][1] = os2; }
        __syncthreads();
        if (tid == 0) {
            pout[blockIdx.x * 2 + 0] = rs[0][0] + rs[1][0] + rs[2][0] + rs[3][0];
            pout[blockIdx.x * 2 + 1] = rs[0][1] + rs[1][1] + rs[2][1] + rs[3][1];
        }
    }
}

// ---------------- final LN + transpose out (B,L,C) -> (B,C,L) ----------------
__global__ __launch_bounds__(256) void k_ln_t(const float* __restrict__ in,
                                              const float* __restrict__ g,
                                              const float* __restrict__ be,
                                              const float* __restrict__ pin,
                                              float* __restrict__ out) {
    __shared__ float tr[64][65];   // [c][l]
    __shared__ float rs[4][2];
    int l0 = blockIdx.x * 64, c0 = blockIdx.y * 64, b = blockIdx.z;
    int tid = threadIdx.x, r = tid >> 2, q = tid & 3;
    float s  = pin[(b * 512 + tid) * 2 + 0] + pin[(b * 512 + 256 + tid) * 2 + 0];
    float s2 = pin[(b * 512 + tid) * 2 + 1] + pin[(b * 512 + 256 + tid) * 2 + 1];
    s = wred_sum(s); s2 = wred_sum(s2);
    if ((tid & 63) == 0) { rs[tid >> 6][0] = s; rs[tid >> 6][1] = s2; }
    __syncthreads();
    float S = rs[0][0] + rs[1][0] + rs[2][0] + rs[3][0];
    float S2 = rs[0][1] + rs[1][1] + rs[2][1] + rs[3][1];
    float mean = S / (float)(CC * LL);
    float inv  = rsqrtf(S2 / (float)(CC * LL) - mean * mean + EPSV);
#pragma unroll
    for (int p = 0; p < 4; ++p) {
        int cc = 4 * (q + 4 * p);
        float4 v  = *(const float4*)&in[((size_t)(b * LL + l0 + r)) * CC + c0 + cc];
        float4 gg = *(const float4*)&g[c0 + cc];
        float4 bb = *(const float4*)&be[c0 + cc];
        tr[cc + 0][r] = (v.x - mean) * inv * gg.x + bb.x;
        tr[cc + 1][r] = (v.y - mean) * inv * gg.y + bb.y;
        tr[cc + 2][r] = (v.z - mean) * inv * gg.z + bb.z;
        tr[cc + 3][r] = (v.w - mean) * inv * gg.w + bb.w;
    }
    __syncthreads();
#pragma unroll
    for (int p = 0; p < 4; ++p) {
        int ll = 4 * (q + 4 * p);
        float4 v = *(const float4*)&tr[r][ll];
        *(float4*)&out[((size_t)(b * CC + c0 + r)) * LL + l0 + ll] = v;
    }
}

// ---------------- launch ----------------
extern "C" void kernel_launch(void* const* d_in, const int* in_sizes, int n_in,
                              void* d_out, int out_size, void* d_ws, size_t ws_size,
                              hipStream_t stream) {
    const float* x      = (const float*)d_in[0];
    const float* Wq     = (const float*)d_in[1];
    const float* bq     = (const float*)d_in[2];
    const float* Wk     = (const float*)d_in[3];
    const float* bk     = (const float*)d_in[4];
    const float* Wv     = (const float*)d_in[5];
    const float* bv     = (const float*)d_in[6];
    const float* Wo     = (const float*)d_in[7];
    const float* bo     = (const float*)d_in[8];
    const float* g_mha  = (const float*)d_in[9];
    const float* b_mha  = (const float*)d_in[10];
    const float* conv_w = (const float*)d_in[11];
    const float* conv_b = (const float*)d_in[12];
    const float* g_ffn  = (const float*)d_in[13];
    const float* b_ffn  = (const float*)d_in[14];
    const float* alpha  = (const float*)d_in[15];
    const float* g_out  = (const float*)d_in[16];
    const float* b_out  = (const float*)d_in[17];
    float* out = (float*)d_out;

    // workspace layout (float units)
    float* ws = (float*)d_ws;
    float* t             = ws;                               // [0, 1,048,576)
    unsigned short* tb   = (unsigned short*)(ws + 1048576);  // [1,048,576, 1,572,864)
    unsigned short* QKVb = (unsigned short*)(ws + 1572864);  // [1,572,864, 4,718,592) 3x2M bf16
    float* f             = ws + 1572864;                     // reuse QKV (dead after attn)
    unsigned short* ybf  = (unsigned short*)(ws + 2621440);  // reuse QKV (dead after attn)
    unsigned short* obuf = (unsigned short*)(ws + 4718592);  // [4,718,592, 5,767,168) op0
    unsigned short* Wqkvb= (unsigned short*)(ws + 5767168);  // 393216 bf16
    unsigned short* Wob  = (unsigned short*)(ws + 5963776);  // 131072 bf16
    unsigned short* Wcb  = (unsigned short*)(ws + 6029312);  // 65536 bf16
    float* pstatA        = ws + 6062080;                     // 512 f
    float* pstatB        = ws + 6062592;                     // 512 f
    float* pstatC        = ws + 6063104;                     // 2048 f
    unsigned short* op1  = (unsigned short*)(ws + 6065152);  // 2M bf16 = 1,048,576 f
    float* lsbuf         = ws + 7113728;                     // 65,536 f  (2 x 16 x 2048)

    k_prep<<<832, 256, 0, stream>>>(x, Wq, Wk, Wv, Wo, conv_w, t, tb, Wqkvb, Wob, Wcb);

    dim3 gqkv(BLQ / 64, 1536 / 64);          // 64,24
    k_mm<<<gqkv, 256, 0, stream>>>(tb, Wqkvb, bq, bk, bv, nullptr, nullptr, QKVb,
                                   nullptr, 1, BLQ, 1536, CC);

    dim3 gattn(HH * BB, LL / 128, 2);        // (16 bh, 16 qt, 2 s-halves) = 512 blocks
    k_attn<<<gattn, 256, 0, stream>>>(QKVb, obuf, op1, lsbuf);
    k_amerge<<<1024, 256, 0, stream>>>(obuf, op1, lsbuf, obuf);

    dim3 go(BLQ / 64, CC / 64);              // 64,4
    k_mm<<<go, 256, 0, stream>>>(obuf, Wob, bo, nullptr, nullptr, t, t, nullptr,
                                 pstatA, 0, BLQ, CC, HDIM);      // t += o@Wo^T+bo, stats

    k_ln<<<1024, 256, 0, stream>>>(t, g_mha, b_mha, pstatA, nullptr, nullptr,
                                   t, ybf, nullptr);             // y := ln(t), + bf16

    k_mm<<<go, 256, 0, stream>>>(ybf, Wcb, conv_b, nullptr, nullptr, nullptr, f, nullptr,
                                 pstatB, 0, BLQ, CC, CC);        // f = y@Wc^T+bc, stats

    k_ln<<<1024, 256, 0, stream>>>(f, g_ffn, b_ffn, pstatB, t, alpha,
                                   f, nullptr, pstatC);          // f := prelu(ln(f)) + y, stats

    k_ln_t<<<dim3(LL / 64, CC / 64, BB), 256, 0, stream>>>(f, g_out, b_out, pstatC, out);
}

// Round 19
// 81.608 us; speedup vs baseline: 1.1075x; 1.0263x over previous
//
#include <hip/hip_runtime.h>
#include <hip/hip_bf16.h>
#include <math.h>

// Problem constants
#define BB   2
#define CC   256
#define LL   2048
#define DD   64
#define HH   8
#define HDIM 512
#define BLQ  (BB*LL)      // 4096 tokens
#define EPSV 1e-8f
#define QSCALE (0.125f * 1.44269504088896f)   // 1/sqrt(64) * log2(e): softmax in exp2 domain

typedef __attribute__((ext_vector_type(8))) short short8;    // 8 bf16 (4 VGPRs)
typedef __attribute__((ext_vector_type(4))) float f32x4;     // 16x16 MFMA acc
typedef __attribute__((ext_vector_type(16))) float f32x16;   // 32x32 MFMA acc

// ---------------- helpers ----------------
__device__ __forceinline__ float wred_sum(float v) {
#pragma unroll
    for (int off = 32; off > 0; off >>= 1) v += __shfl_down(v, off, 64);
    return v;
}
// HW packed fp32x2 -> bf16x2 (RNE), single v_cvt_pk_bf16_f32
__device__ __forceinline__ unsigned pk(float a, float b) {
    unsigned r;
    asm("v_cvt_pk_bf16_f32 %0, %1, %2" : "=v"(r) : "v"(a), "v"(b));
    return r;
}
// bare HW exp2 / log2 (softmax runs in the exp2 domain; libm paths are multi-instr)
__device__ __forceinline__ float ex2(float x) {
    float r;
    asm("v_exp_f32 %0, %1" : "=v"(r) : "v"(x));
    return r;
}
__device__ __forceinline__ float lg2(float x) {
    float r;
    asm("v_log_f32 %0, %1" : "=v"(r) : "v"(x));
    return r;
}
__device__ __forceinline__ float bf2f(unsigned short v) {
    union { unsigned u; float f; } c; c.u = ((unsigned)v) << 16; return c.f;
}
// cross-half register swap: x[0:31] <-> y[32:63]  (v_permlane32_swap_b32; verified r6)
__device__ __forceinline__ void pswap(unsigned &x, unsigned &y) {
    asm("v_permlane32_swap_b32 %0, %1" : "+v"(x), "+v"(y));
}
__device__ __forceinline__ short8 mk8(unsigned x0, unsigned x1, unsigned x2, unsigned x3) {
    union { short8 v; unsigned u[4]; } r;
    r.u[0] = x0; r.u[1] = x1; r.u[2] = x2; r.u[3] = x3;
    return r.v;
}
// assemble a bf16x8 fragment from two 8B LDS loads (stride-68, measured-low-conflict)
__device__ __forceinline__ short8 ld_frag(const unsigned short* p) {
    union { short8 v; uint2 u[2]; } f;
    f.u[0] = *(const uint2*)p;
    f.u[1] = *(const uint2*)(p + 4);
    return f.v;
}

// ---------------- prep (fused): t = x^T + PE  AND  weight fp32->bf16 convert ----------
__global__ __launch_bounds__(256) void k_prep(const float* __restrict__ x,
                                              const float* __restrict__ Wq, const float* __restrict__ Wk,
                                              const float* __restrict__ Wv, const float* __restrict__ Wo,
                                              const float* __restrict__ Wc,
                                              float* __restrict__ t,
                                              unsigned short* __restrict__ tb,
                                              unsigned short* __restrict__ dqkv,
                                              unsigned short* __restrict__ dWo,
                                              unsigned short* __restrict__ dWc) {
    int bid = blockIdx.x;
    int tid = threadIdx.x;
    if (bid >= 256) {   // ---- weight convert: 576 blocks * 256 thr * 4 elems ----
        int idx = ((bid - 256) * 256 + tid) * 4;
        const float* s; unsigned short* d;
        if (idx < 131072)      { s = Wq + idx;          d = dqkv + idx; }
        else if (idx < 262144) { s = Wk + idx - 131072; d = dqkv + idx; }
        else if (idx < 393216) { s = Wv + idx - 262144; d = dqkv + idx; }
        else if (idx < 524288) { s = Wo + idx - 393216; d = dWo + idx - 393216; }
        else                   { s = Wc + idx - 524288; d = dWc + idx - 524288; }
        float4 v = *(const float4*)s;
        uint2 u; u.x = pk(v.x, v.y); u.y = pk(v.z, v.w);
        *(uint2*)d = u;
        return;
    }
    // ---- transpose + positional encoding ----
    __shared__ float tr[64][65];    // [l][c]
    int l0 = (bid & 31) * 64, c0 = ((bid >> 5) & 3) * 64, b = bid >> 7;
    int r = tid >> 2, q = tid & 3;
#pragma unroll
    for (int p = 0; p < 4; ++p) {
        int lc = 4 * (q + 4 * p);
        float4 v = *(const float4*)&x[((size_t)(b * CC + c0 + r)) * LL + l0 + lc];
        tr[lc + 0][r] = v.x; tr[lc + 1][r] = v.y; tr[lc + 2][r] = v.z; tr[lc + 3][r] = v.w;
    }
    __syncthreads();
    int lg = l0 + r;
#pragma unroll
    for (int p = 0; p < 4; ++p) {
        int cc = 4 * (q + 4 * p);
        float4 v = *(const float4*)&tr[r][cc];
        float pe[4];
#pragma unroll
        for (int i = 0; i < 4; ++i) {
            int cg = c0 + cc + i;
            float freq = __expf((float)(cg & ~1) * (-9.210340371976184f / (float)CC));
            float ang = (float)lg * freq;
            pe[i] = (cg & 1) ? __cosf(ang) : __sinf(ang);
        }
        v.x += pe[0]; v.y += pe[1]; v.z += pe[2]; v.w += pe[3];
        size_t o = ((size_t)(b * LL + lg)) * CC + c0 + cc;
        *(float4*)&t[o] = v;
        uint2 u; u.x = pk(v.x, v.y); u.y = pk(v.z, v.w);
        *(uint2*)&tb[o] = u;
    }
}

// ---------------- MFMA GEMM: out = A @ W^T (+bias) (+resid) (+partial LN stats) --------
// mode 0: fp32 out, bias b0, optional resid (may alias out), optional pstat.
// mode 1: QKV epilogue (Q/K (B,H,L,D) bf16, V transposed (B,H,D,L) bf16).
// r15 lesson: no extra work in the A-staging path (barrier-exposed).
// r17 lesson: 128^2 tile with K<=256 regressed (short K can't amortize); keep 64^2.
#define MLDK 68
__global__ __launch_bounds__(256) void k_mm(const unsigned short* __restrict__ A,
                                            const unsigned short* __restrict__ W,
                                            const float* __restrict__ b0,
                                            const float* __restrict__ b1,
                                            const float* __restrict__ b2,
                                            const float* resid,
                                            float* out, unsigned short* outb,
                                            float* pstat,
                                            int mode, int M, int N, int K) {
    __shared__ unsigned short As[2][64][MLDK];
    __shared__ unsigned short Ws[2][64][MLDK];
    __shared__ float rs[4][2];
    int tid = threadIdx.x;
    int w = tid >> 6, lane = tid & 63, g = lane >> 4, qi = lane & 15;
    int bm = blockIdx.x * 64, bn = blockIdx.y * 64;
    int wr = w >> 1, wc = w & 1;
    int srow = tid >> 2, sq = tid & 3;
    bool vseg = (mode == 1) && (bn >= 1024);
    f32x4 acc[2][2];
    acc[0][0] = acc[0][1] = acc[1][0] = acc[1][1] = (f32x4){0.f, 0.f, 0.f, 0.f};
    uint4 ra[2], rw[2];
#pragma unroll
    for (int p = 0; p < 2; ++p) {
        ra[p] = *(const uint4*)&A[(size_t)(bm + srow) * K + (sq + 4 * p) * 8];
        rw[p] = *(const uint4*)&W[(size_t)(bn + srow) * K + (sq + 4 * p) * 8];
    }
    int nt = K >> 6;
    for (int it = 0; it < nt; ++it) {
        int buf = it & 1;
#pragma unroll
        for (int p = 0; p < 2; ++p) {
            *(uint2*)&As[buf][srow][(sq + 4 * p) * 8]     = make_uint2(ra[p].x, ra[p].y);
            *(uint2*)&As[buf][srow][(sq + 4 * p) * 8 + 4] = make_uint2(ra[p].z, ra[p].w);
            *(uint2*)&Ws[buf][srow][(sq + 4 * p) * 8]     = make_uint2(rw[p].x, rw[p].y);
            *(uint2*)&Ws[buf][srow][(sq + 4 * p) * 8 + 4] = make_uint2(rw[p].z, rw[p].w);
        }
        __syncthreads();
        if (it + 1 < nt) {
            int k0 = (it + 1) << 6;
#pragma unroll
            for (int p = 0; p < 2; ++p) {
                ra[p] = *(const uint4*)&A[(size_t)(bm + srow) * K + k0 + (sq + 4 * p) * 8];
                rw[p] = *(const uint4*)&W[(size_t)(bn + srow) * K + k0 + (sq + 4 * p) * 8];
            }
        }
#pragma unroll
        for (int c = 0; c < 2; ++c) {
            short8 wf0 = ld_frag(&Ws[buf][wr * 32 + 0  + qi][c * 32 + 8 * g]);
            short8 wf1 = ld_frag(&Ws[buf][wr * 32 + 16 + qi][c * 32 + 8 * g]);
            short8 af0 = ld_frag(&As[buf][wc * 32 + 0  + qi][c * 32 + 8 * g]);
            short8 af1 = ld_frag(&As[buf][wc * 32 + 16 + qi][c * 32 + 8 * g]);
            if (!vseg) {
                acc[0][0] = __builtin_amdgcn_mfma_f32_16x16x32_bf16(wf0, af0, acc[0][0], 0, 0, 0);
                acc[0][1] = __builtin_amdgcn_mfma_f32_16x16x32_bf16(wf0, af1, acc[0][1], 0, 0, 0);
                acc[1][0] = __builtin_amdgcn_mfma_f32_16x16x32_bf16(wf1, af0, acc[1][0], 0, 0, 0);
                acc[1][1] = __builtin_amdgcn_mfma_f32_16x16x32_bf16(wf1, af1, acc[1][1], 0, 0, 0);
            } else {
                acc[0][0] = __builtin_amdgcn_mfma_f32_16x16x32_bf16(af0, wf0, acc[0][0], 0, 0, 0);
                acc[0][1] = __builtin_amdgcn_mfma_f32_16x16x32_bf16(af0, wf1, acc[0][1], 0, 0, 0);
                acc[1][0] = __builtin_amdgcn_mfma_f32_16x16x32_bf16(af1, wf0, acc[1][0], 0, 0, 0);
                acc[1][1] = __builtin_amdgcn_mfma_f32_16x16x32_bf16(af1, wf1, acc[1][1], 0, 0, 0);
            }
        }
    }
    if (mode == 0) {
        float s = 0.f, s2 = 0.f;
#pragma unroll
        for (int fi = 0; fi < 2; ++fi)
#pragma unroll
            for (int fj = 0; fj < 2; ++fj) {
                int n0 = bn + wr * 32 + fi * 16 + 4 * g;
                int m  = bm + wc * 32 + fj * 16 + qi;
                float4 bi = *(const float4*)&b0[n0];
                float4 v;
                v.x = acc[fi][fj][0] + bi.x; v.y = acc[fi][fj][1] + bi.y;
                v.z = acc[fi][fj][2] + bi.z; v.w = acc[fi][fj][3] + bi.w;
                if (resid) {
                    float4 rv = *(const float4*)&resid[(size_t)m * N + n0];
                    v.x += rv.x; v.y += rv.y; v.z += rv.z; v.w += rv.w;
                }
                *(float4*)&out[(size_t)m * N + n0] = v;
                s  += (v.x + v.y) + (v.z + v.w);
                s2 += v.x * v.x + v.y * v.y + v.z * v.z + v.w * v.w;
            }
        if (pstat) {
            s = wred_sum(s); s2 = wred_sum(s2);
            if (lane == 0) { rs[w][0] = s; rs[w][1] = s2; }
            __syncthreads();
            if (tid == 0) {
                int bid = blockIdx.y * gridDim.x + blockIdx.x;
                pstat[bid * 2 + 0] = rs[0][0] + rs[1][0] + rs[2][0] + rs[3][0];
                pstat[bid * 2 + 1] = rs[0][1] + rs[1][1] + rs[2][1] + rs[3][1];
            }
        }
    } else if (!vseg) {
        int seg = bn >> 9;                      // 0 = Q, 1 = K
        const float* bs = seg ? b1 : b0;
        float sc = seg ? 1.f : QSCALE;
#pragma unroll
        for (int fi = 0; fi < 2; ++fi)
#pragma unroll
            for (int fj = 0; fj < 2; ++fj) {
                int nn0 = (bn & 511) + wr * 32 + fi * 16 + 4 * g;
                int m   = bm + wc * 32 + fj * 16 + qi;
                int b = m >> 11, l = m & (LL - 1);
                int h = nn0 >> 6, d0 = nn0 & 63;
                float4 bi = *(const float4*)&bs[nn0];
                uint2 u;
                u.x = pk(sc * (acc[fi][fj][0] + bi.x), sc * (acc[fi][fj][1] + bi.y));
                u.y = pk(sc * (acc[fi][fj][2] + bi.z), sc * (acc[fi][fj][3] + bi.w));
                *(uint2*)&outb[(size_t)seg * 2097152 +
                               (((size_t)(b * HH + h)) * LL + l) * DD + d0] = u;
            }
    } else {
#pragma unroll
        for (int fi = 0; fi < 2; ++fi)
#pragma unroll
            for (int fj = 0; fj < 2; ++fj) {
                int m0 = bm + wc * 32 + fi * 16 + 4 * g;
                int nn = (bn & 511) + wr * 32 + fj * 16 + qi;
                int b = m0 >> 11, l0 = m0 & (LL - 1);
                int h = nn >> 6, d = nn & 63;
                float bi = b2[nn];
                uint2 u;
                u.x = pk(acc[fi][fj][0] + bi, acc[fi][fj][1] + bi);
                u.y = pk(acc[fi][fj][2] + bi, acc[fi][fj][3] + bi);
                *(uint2*)&outb[(size_t)2 * 2097152 +
                               (((size_t)(b * HH + h)) * DD + d) * LL + l0] = u;
            }
    }
}

// ---------------- MFMA flash attention: 32x32 + LDS staging + in-reg P + joint softmax --
// r14 structure (verified absmax 0.0625) with r19 change: both 32-s subtiles' QK^T are
// computed first (8 back-to-back MFMAs), then ONE joint softmax pass over all 64 keys
// (1 max-tree+shfl+defer instead of 2), then all 8 PV MFMAs. Same math, exact.
#define LDK 68
__global__ __launch_bounds__(256) void k_attn(const unsigned short* __restrict__ QKV,
                                              unsigned short* __restrict__ op0,
                                              unsigned short* __restrict__ op1,
                                              float* __restrict__ ls) {
    int bh = blockIdx.x;               // b*8 + h  (XCD-pinned: id%8 = bh%8)
    int h = bh & 7, b = bh >> 3;
    int z = blockIdx.z;
    int sb0 = z << 10;                 // this block's s-range start (1024 keys, 16 tiles)
    int tid = threadIdx.x;
    int w = tid >> 6, lane = tid & 63;
    int lo31 = lane & 31, hi = lane >> 5;
    int q0 = blockIdx.y * 128 + w * 32;
    __shared__ unsigned short Ks[2][64][LDK];    // [s][d]
    __shared__ unsigned short Vts[2][64][LDK];   // [d][s]
    const unsigned short* Qg = QKV + (size_t)bh * LL * DD;
    const unsigned short* Kg = QKV + 2097152 + (size_t)bh * LL * DD;
    const unsigned short* Vg = QKV + (size_t)2 * 2097152 + (size_t)bh * DD * LL;

    short8 qf[4];
#pragma unroll
    for (int c = 0; c < 4; ++c)
        qf[c] = *(const short8*)&Qg[(size_t)(q0 + lo31) * DD + c * 16 + 8 * hi];

    f32x16 o0, o1;
#pragma unroll
    for (int r = 0; r < 16; ++r) { o0[r] = 0.f; o1[r] = 0.f; }
    float m = -INFINITY, sum = 0.f;

    int srow = tid >> 2, sq = tid & 3;
    uint4 kr[2], vr[2];
#pragma unroll
    for (int p = 0; p < 2; ++p) {
        kr[p] = *(const uint4*)&Kg[(size_t)(sb0 + srow) * DD + (sq + 4 * p) * 8];
        vr[p] = *(const uint4*)&Vg[(size_t)srow * LL + sb0 + (sq + 4 * p) * 8];
    }
    for (int it = 0; it < 16; ++it) {
        int buf = it & 1;
#pragma unroll
        for (int p = 0; p < 2; ++p) {
            *(uint2*)&Ks[buf][srow][(sq + 4 * p) * 8]      = make_uint2(kr[p].x, kr[p].y);
            *(uint2*)&Ks[buf][srow][(sq + 4 * p) * 8 + 4]  = make_uint2(kr[p].z, kr[p].w);
            *(uint2*)&Vts[buf][srow][(sq + 4 * p) * 8]     = make_uint2(vr[p].x, vr[p].y);
            *(uint2*)&Vts[buf][srow][(sq + 4 * p) * 8 + 4] = make_uint2(vr[p].z, vr[p].w);
        }
        __syncthreads();
        if (it + 1 < 16) {
            int s1 = sb0 + (it + 1) * 64;
#pragma unroll
            for (int p = 0; p < 2; ++p) {
                kr[p] = *(const uint4*)&Kg[(size_t)(s1 + srow) * DD + (sq + 4 * p) * 8];
                vr[p] = *(const uint4*)&Vg[(size_t)srow * LL + s1 + (sq + 4 * p) * 8];
            }
        }
        // QK^T for BOTH subtiles: 8 back-to-back MFMAs (st0: s 0-31, st1: s 32-63)
        f32x16 st0, st1;
#pragma unroll
        for (int r = 0; r < 16; ++r) { st0[r] = 0.f; st1[r] = 0.f; }
        __builtin_amdgcn_s_setprio(1);
#pragma unroll
        for (int c = 0; c < 4; ++c) {
            short8 kf0 = ld_frag(&Ks[buf][lo31][c * 16 + 8 * hi]);
            short8 kf1 = ld_frag(&Ks[buf][32 + lo31][c * 16 + 8 * hi]);
            st0 = __builtin_amdgcn_mfma_f32_32x32x16_bf16(kf0, qf[c], st0, 0, 0, 0);
            st1 = __builtin_amdgcn_mfma_f32_32x32x16_bf16(kf1, qf[c], st1, 0, 0, 0);
        }
        __builtin_amdgcn_s_setprio(0);
        // joint per-q max over all 64 keys (1 tree + 1 shfl + 1 defer instead of 2)
        float t0 = fmaxf(fmaxf(st0[0], st0[1]),   fmaxf(st0[2], st0[3]));
        float t1 = fmaxf(fmaxf(st0[4], st0[5]),   fmaxf(st0[6], st0[7]));
        float t2 = fmaxf(fmaxf(st0[8], st0[9]),   fmaxf(st0[10], st0[11]));
        float t3 = fmaxf(fmaxf(st0[12], st0[13]), fmaxf(st0[14], st0[15]));
        float t4 = fmaxf(fmaxf(st1[0], st1[1]),   fmaxf(st1[2], st1[3]));
        float t5 = fmaxf(fmaxf(st1[4], st1[5]),   fmaxf(st1[6], st1[7]));
        float t6 = fmaxf(fmaxf(st1[8], st1[9]),   fmaxf(st1[10], st1[11]));
        float t7 = fmaxf(fmaxf(st1[12], st1[13]), fmaxf(st1[14], st1[15]));
        float tmax = fmaxf(fmaxf(fmaxf(t0, t1), fmaxf(t2, t3)),
                           fmaxf(fmaxf(t4, t5), fmaxf(t6, t7)));
        tmax = fmaxf(tmax, __shfl_xor(tmax, 32, 64));
        // T13 defer-max (2^8 headroom)
        if (!__all(tmax - m <= 8.f)) {
            float mnew = fmaxf(m, tmax);
            float corr = ex2(m - mnew);
            m = mnew;
            sum *= corr;
#pragma unroll
            for (int r = 0; r < 16; ++r) { o0[r] *= corr; o1[r] *= corr; }
        }
        float p0[16], p1[16];
#pragma unroll
        for (int r = 0; r < 16; ++r) { p0[r] = ex2(st0[r] - m); p1[r] = ex2(st1[r] - m); }
        float sA = ((p0[0] + p0[1])   + (p0[2] + p0[3]))  + ((p0[4] + p0[5])   + (p0[6] + p0[7]));
        float sB = ((p0[8] + p0[9])   + (p0[10] + p0[11])) + ((p0[12] + p0[13]) + (p0[14] + p0[15]));
        float sC = ((p1[0] + p1[1])   + (p1[2] + p1[3]))  + ((p1[4] + p1[5])   + (p1[6] + p1[7]));
        float sD = ((p1[8] + p1[9])   + (p1[10] + p1[11])) + ((p1[12] + p1[13]) + (p1[14] + p1[15]));
        sum += (sA + sB) + (sC + sD);
        // pack both subtiles' P -> 4 PV B-fragments (cvt_pk + permlane32_swap)
        unsigned a0 = pk(p0[0], p0[1]),   a1 = pk(p0[2], p0[3]);
        unsigned a2 = pk(p0[4], p0[5]),   a3 = pk(p0[6], p0[7]);
        pswap(a2, a0); pswap(a3, a1);
        unsigned a4 = pk(p0[8], p0[9]),   a5 = pk(p0[10], p0[11]);
        unsigned a6 = pk(p0[12], p0[13]), a7 = pk(p0[14], p0[15]);
        pswap(a6, a4); pswap(a7, a5);
        unsigned b0_ = pk(p1[0], p1[1]),   b1_ = pk(p1[2], p1[3]);
        unsigned b2_ = pk(p1[4], p1[5]),   b3_ = pk(p1[6], p1[7]);
        pswap(b2_, b0_); pswap(b3_, b1_);
        unsigned b4_ = pk(p1[8], p1[9]),   b5_ = pk(p1[10], p1[11]);
        unsigned b6_ = pk(p1[12], p1[13]), b7_ = pk(p1[14], p1[15]);
        pswap(b6_, b4_); pswap(b7_, b5_);
        short8 pb00 = mk8(a0, a1, a2, a3);   // k = 0..15
        short8 pb01 = mk8(a4, a5, a6, a7);   // k = 16..31
        short8 pb10 = mk8(b0_, b1_, b2_, b3_); // k = 32..47
        short8 pb11 = mk8(b4_, b5_, b6_, b7_); // k = 48..63
        // PV: all 8 MFMAs for the 64-key tile
        __builtin_amdgcn_s_setprio(1);
        {
            short8 vf00 = ld_frag(&Vts[buf][lo31][8 * hi]);
            short8 vf01 = ld_frag(&Vts[buf][lo31][16 + 8 * hi]);
            short8 vf02 = ld_frag(&Vts[buf][lo31][32 + 8 * hi]);
            short8 vf03 = ld_frag(&Vts[buf][lo31][48 + 8 * hi]);
            short8 vf10 = ld_frag(&Vts[buf][32 + lo31][8 * hi]);
            short8 vf11 = ld_frag(&Vts[buf][32 + lo31][16 + 8 * hi]);
            short8 vf12 = ld_frag(&Vts[buf][32 + lo31][32 + 8 * hi]);
            short8 vf13 = ld_frag(&Vts[buf][32 + lo31][48 + 8 * hi]);
            o0 = __builtin_amdgcn_mfma_f32_32x32x16_bf16(vf00, pb00, o0, 0, 0, 0);
            o0 = __builtin_amdgcn_mfma_f32_32x32x16_bf16(vf01, pb01, o0, 0, 0, 0);
            o0 = __builtin_amdgcn_mfma_f32_32x32x16_bf16(vf02, pb10, o0, 0, 0, 0);
            o0 = __builtin_amdgcn_mfma_f32_32x32x16_bf16(vf03, pb11, o0, 0, 0, 0);
            o1 = __builtin_amdgcn_mfma_f32_32x32x16_bf16(vf10, pb00, o1, 0, 0, 0);
            o1 = __builtin_amdgcn_mfma_f32_32x32x16_bf16(vf11, pb01, o1, 0, 0, 0);
            o1 = __builtin_amdgcn_mfma_f32_32x32x16_bf16(vf12, pb10, o1, 0, 0, 0);
            o1 = __builtin_amdgcn_mfma_f32_32x32x16_bf16(vf13, pb11, o1, 0, 0, 0);
        }
        __builtin_amdgcn_s_setprio(0);
    }
    sum += __shfl_xor(sum, 32, 64);
    float rinv = 1.f / sum;
    unsigned short* op = z ? op1 : op0;
    size_t base = ((size_t)(b * LL + q0 + lo31)) * HDIM + h * DD;
#pragma unroll
    for (int j = 0; j < 4; ++j) {
        int d0 = 8 * j + 4 * hi;
        uint2 u;
        u.x = pk(o0[4 * j + 0] * rinv, o0[4 * j + 1] * rinv);
        u.y = pk(o0[4 * j + 2] * rinv, o0[4 * j + 3] * rinv);
        *(uint2*)&op[base + d0] = u;
        uint2 u1;
        u1.x = pk(o1[4 * j + 0] * rinv, o1[4 * j + 1] * rinv);
        u1.y = pk(o1[4 * j + 2] * rinv, o1[4 * j + 3] * rinv);
        *(uint2*)&op[base + 32 + d0] = u1;
    }
    if (hi == 0) ls[(z << 15) + bh * LL + q0 + lo31] = m + lg2(sum);
}

// ---------------- merge of the 2 split-S partials (exact softmax combine, verified r13) --
__global__ __launch_bounds__(256) void k_amerge(const unsigned short* op0,
                                                const unsigned short* op1,
                                                const float* __restrict__ ls,
                                                unsigned short* out) {
    int flat = (blockIdx.x * 256 + threadIdx.x) * 8;
    int tt = flat >> 9;                   // token = b*LL + l
    int h  = (flat >> 6) & 7;
    int b  = tt >> 11, l = tt & (LL - 1);
    int bh = b * HH + h;
    float l0 = ls[bh * LL + l];
    float l1 = ls[(1 << 15) + bh * LL + l];
    float M  = fmaxf(l0, l1);
    float w0 = ex2(l0 - M), w1 = ex2(l1 - M);
    float inv = 1.f / (w0 + w1);
    w0 *= inv; w1 *= inv;
    uint4 a = *(const uint4*)&op0[flat];
    uint4 c = *(const uint4*)&op1[flat];
    const unsigned* au = (const unsigned*)&a;
    const unsigned* cu = (const unsigned*)&c;
    uint4 r;
    unsigned* ru = (unsigned*)&r;
#pragma unroll
    for (int i = 0; i < 4; ++i) {
        float a0 = bf2f((unsigned short)(au[i] & 0xffff));
        float a1 = bf2f((unsigned short)(au[i] >> 16));
        float c0 = bf2f((unsigned short)(cu[i] & 0xffff));
        float c1 = bf2f((unsigned short)(cu[i] >> 16));
        ru[i] = pk(w0 * a0 + w1 * c0, w0 * a1 + w1 * c1);
    }
    *(uint4*)&out[flat] = r;
}

// ---------------- LN apply, vectorized (+PReLU, +add, +bf16 copy, +out partials) ------
__global__ __launch_bounds__(256) void k_ln(const float* in,
                                            const float* __restrict__ g,
                                            const float* __restrict__ be,
                                            const float* __restrict__ pin,
                                            const float* __restrict__ add,
                                            const float* __restrict__ alpha_ptr,
                                            float* out, unsigned short* outb,
                                            float* pout) {
    __shared__ float rs[4][2];
    int tid = threadIdx.x;
    int b = blockIdx.x >> 9;           // 512 blocks per batch
    float s = 0.f, s2 = 0.f;
    if (tid < 128) {
        int pidx = (tid >> 5) * 64 + b * 32 + (tid & 31);
        s  = pin[pidx * 2 + 0];
        s2 = pin[pidx * 2 + 1];
    }
    s = wred_sum(s); s2 = wred_sum(s2);
    if ((tid & 63) == 0 && tid < 128) { rs[tid >> 6][0] = s; rs[tid >> 6][1] = s2; }
    __syncthreads();
    float S = rs[0][0] + rs[1][0], S2 = rs[0][1] + rs[1][1];
    float mean = S / (float)(CC * LL);
    float inv  = rsqrtf(S2 / (float)(CC * LL) - mean * mean + EPSV);

    int idx = (blockIdx.x * 256 + tid) * 4;
    int c = idx & (CC - 1);
    float4 v  = *(const float4*)&in[idx];
    float4 gg = *(const float4*)&g[c];
    float4 bb = *(const float4*)&be[c];
    v.x = (v.x - mean) * inv * gg.x + bb.x;
    v.y = (v.y - mean) * inv * gg.y + bb.y;
    v.z = (v.z - mean) * inv * gg.z + bb.z;
    v.w = (v.w - mean) * inv * gg.w + bb.w;
    if (alpha_ptr) {
        float al = alpha_ptr[0];
        v.x = v.x >= 0.f ? v.x : al * v.x;
        v.y = v.y >= 0.f ? v.y : al * v.y;
        v.z = v.z >= 0.f ? v.z : al * v.z;
        v.w = v.w >= 0.f ? v.w : al * v.w;
    }
    if (add) {
        float4 a = *(const float4*)&add[idx];
        v.x += a.x; v.y += a.y; v.z += a.z; v.w += a.w;
    }
    *(float4*)&out[idx] = v;
    if (outb) {
        uint2 u; u.x = pk(v.x, v.y); u.y = pk(v.z, v.w);
        *(uint2*)&outb[idx] = u;
    }
    if (pout) {
        float os  = (v.x + v.y) + (v.z + v.w);
        float os2 = v.x * v.x + v.y * v.y + v.z * v.z + v.w * v.w;
        os = wred_sum(os); os2 = wred_sum(os2);
        __syncthreads();   // rs reuse
        if ((tid & 63) == 0) { rs[tid >> 6][0] = os; rs[tid >> 6][1] = os2; }
        __syncthreads();
        if (tid == 0) {
            pout[blockIdx.x * 2 + 0] = rs[0][0] + rs[1][0] + rs[2][0] + rs[3][0];
            pout[blockIdx.x * 2 + 1] = rs[0][1] + rs[1][1] + rs[2][1] + rs[3][1];
        }
    }
}

// ---------------- final LN + transpose out (B,L,C) -> (B,C,L) ----------------
__global__ __launch_bounds__(256) void k_ln_t(const float* __restrict__ in,
                                              const float* __restrict__ g,
                                              const float* __restrict__ be,
                                              const float* __restrict__ pin,
                                              float* __restrict__ out) {
    __shared__ float tr[64][65];   // [c][l]
    __shared__ float rs[4][2];
    int l0 = blockIdx.x * 64, c0 = blockIdx.y * 64, b = blockIdx.z;
    int tid = threadIdx.x, r = tid >> 2, q = tid & 3;
    float s  = pin[(b * 512 + tid) * 2 + 0] + pin[(b * 512 + 256 + tid) * 2 + 0];
    float s2 = pin[(b * 512 + tid) * 2 + 1] + pin[(b * 512 + 256 + tid) * 2 + 1];
    s = wred_sum(s); s2 = wred_sum(s2);
    if ((tid & 63) == 0) { rs[tid >> 6][0] = s; rs[tid >> 6][1] = s2; }
    __syncthreads();
    float S = rs[0][0] + rs[1][0] + rs[2][0] + rs[3][0];
    float S2 = rs[0][1] + rs[1][1] + rs[2][1] + rs[3][1];
    float mean = S / (float)(CC * LL);
    float inv  = rsqrtf(S2 / (float)(CC * LL) - mean * mean + EPSV);
#pragma unroll
    for (int p = 0; p < 4; ++p) {
        int cc = 4 * (q + 4 * p);
        float4 v  = *(const float4*)&in[((size_t)(b * LL + l0 + r)) * CC + c0 + cc];
        float4 gg = *(const float4*)&g[c0 + cc];
        float4 bb = *(const float4*)&be[c0 + cc];
        tr[cc + 0][r] = (v.x - mean) * inv * gg.x + bb.x;
        tr[cc + 1][r] = (v.y - mean) * inv * gg.y + bb.y;
        tr[cc + 2][r] = (v.z - mean) * inv * gg.z + bb.z;
        tr[cc + 3][r] = (v.w - mean) * inv * gg.w + bb.w;
    }
    __syncthreads();
#pragma unroll
    for (int p = 0; p < 4; ++p) {
        int ll = 4 * (q + 4 * p);
        float4 v = *(const float4*)&tr[r][ll];
        *(float4*)&out[((size_t)(b * CC + c0 + r)) * LL + l0 + ll] = v;
    }
}

// ---------------- launch ----------------
extern "C" void kernel_launch(void* const* d_in, const int* in_sizes, int n_in,
                              void* d_out, int out_size, void* d_ws, size_t ws_size,
                              hipStream_t stream) {
    const float* x      = (const float*)d_in[0];
    const float* Wq     = (const float*)d_in[1];
    const float* bq     = (const float*)d_in[2];
    const float* Wk     = (const float*)d_in[3];
    const float* bk     = (const float*)d_in[4];
    const float* Wv     = (const float*)d_in[5];
    const float* bv     = (const float*)d_in[6];
    const float* Wo     = (const float*)d_in[7];
    const float* bo     = (const float*)d_in[8];
    const float* g_mha  = (const float*)d_in[9];
    const float* b_mha  = (const float*)d_in[10];
    const float* conv_w = (const float*)d_in[11];
    const float* conv_b = (const float*)d_in[12];
    const float* g_ffn  = (const float*)d_in[13];
    const float* b_ffn  = (const float*)d_in[14];
    const float* alpha  = (const float*)d_in[15];
    const float* g_out  = (const float*)d_in[16];
    const float* b_out  = (const float*)d_in[17];
    float* out = (float*)d_out;

    // workspace layout (float units)
    float* ws = (float*)d_ws;
    float* t             = ws;                               // [0, 1,048,576)
    unsigned short* tb   = (unsigned short*)(ws + 1048576);  // [1,048,576, 1,572,864)
    unsigned short* QKVb = (unsigned short*)(ws + 1572864);  // [1,572,864, 4,718,592) 3x2M bf16
    float* f             = ws + 1572864;                     // reuse QKV (dead after attn)
    unsigned short* ybf  = (unsigned short*)(ws + 2621440);  // reuse QKV (dead after attn)
    unsigned short* obuf = (unsigned short*)(ws + 4718592);  // [4,718,592, 5,767,168) op0
    unsigned short* Wqkvb= (unsigned short*)(ws + 5767168);  // 393216 bf16
    unsigned short* Wob  = (unsigned short*)(ws + 5963776);  // 131072 bf16
    unsigned short* Wcb  = (unsigned short*)(ws + 6029312);  // 65536 bf16
    float* pstatA        = ws + 6062080;                     // 512 f
    float* pstatB        = ws + 6062592;                     // 512 f
    float* pstatC        = ws + 6063104;                     // 2048 f
    unsigned short* op1  = (unsigned short*)(ws + 6065152);  // 2M bf16 = 1,048,576 f
    float* lsbuf         = ws + 7113728;                     // 65,536 f  (2 x 16 x 2048)

    k_prep<<<832, 256, 0, stream>>>(x, Wq, Wk, Wv, Wo, conv_w, t, tb, Wqkvb, Wob, Wcb);

    dim3 gqkv(BLQ / 64, 1536 / 64);          // 64,24
    k_mm<<<gqkv, 256, 0, stream>>>(tb, Wqkvb, bq, bk, bv, nullptr, nullptr, QKVb,
                                   nullptr, 1, BLQ, 1536, CC);

    dim3 gattn(HH * BB, LL / 128, 2);        // (16 bh, 16 qt, 2 s-halves) = 512 blocks
    k_attn<<<gattn, 256, 0, stream>>>(QKVb, obuf, op1, lsbuf);
    k_amerge<<<1024, 256, 0, stream>>>(obuf, op1, lsbuf, obuf);

    dim3 go(BLQ / 64, CC / 64);              // 64,4
    k_mm<<<go, 256, 0, stream>>>(obuf, Wob, bo, nullptr, nullptr, t, t, nullptr,
                                 pstatA, 0, BLQ, CC, HDIM);      // t += o@Wo^T+bo, stats

    k_ln<<<1024, 256, 0, stream>>>(t, g_mha, b_mha, pstatA, nullptr, nullptr,
                                   t, ybf, nullptr);             // y := ln(t), + bf16

    k_mm<<<go, 256, 0, stream>>>(ybf, Wcb, conv_b, nullptr, nullptr, nullptr, f, nullptr,
                                 pstatB, 0, BLQ, CC, CC);        // f = y@Wc^T+bc, stats

    k_ln<<<1024, 256, 0, stream>>>(f, g_ffn, b_ffn, pstatB, t, alpha,
                                   f, nullptr, pstatC);          // f := prelu(ln(f)) + y, stats

    k_ln_t<<<dim3(LL / 64, CC / 64, BB), 256, 0, stream>>>(f, g_out, b_out, pstatC, out);
}